// Round 2
// baseline (183.041 us; speedup 1.0000x reference)
//
#include <hip/hip_runtime.h>
#include <cmath>

#define NDEV   100000
#define NBATCH 8192
#define CONTF  62
#define EMB    16
#define FEAT   94      // 62 + 16 + 16
#define KNBR   64
#define NH     4
#define OUTD   16
#define HOUT   64      // NH*OUTD
#define FUS    204     // 94 + 94 + 16
#define ALPHA  0.2f

#define NDEVG2  782    // ceil(100000/128) row-groups
#define NCOMBG2 64     // 8192/128 row-groups
#define KP      48     // K-pairs incl. zero pad (96 bf16 = 48 uints)

typedef unsigned short ushortT;
typedef unsigned int   uintT;
typedef ushortT ushort8v __attribute__((ext_vector_type(8)));
typedef short   short8  __attribute__((ext_vector_type(8)));
typedef float   float4v __attribute__((ext_vector_type(4)));

// ---------------- workspace layout (float slots) ----------------
// h_bf  : NDEV*64 bf16 = 3,200,000 @ 0   (12.8 MB)
// e_d   : NDEV*4       =   400,000 @ 3,200,000
// e_c   : NBATCH*4     =    32,768 @ 3,600,000

template <typename T>
__device__ __forceinline__ const T* uniform_ptr(const T* p) {
  uint64_t v = (uint64_t)(uintptr_t)p;
  uint32_t lo = __builtin_amdgcn_readfirstlane((uint32_t)v);
  uint32_t hi = __builtin_amdgcn_readfirstlane((uint32_t)(v >> 32));
  return (const T*)(uintptr_t)(((uint64_t)hi << 32) | lo);
}

__device__ __forceinline__ float bf2f(ushortT u) {
  return __uint_as_float(((unsigned int)u) << 16);
}
__device__ __forceinline__ ushortT f2bf(float f) {
  unsigned int i = __float_as_uint(f);
  unsigned int r = i + 0x7FFFu + ((i >> 16) & 1u);  // round-to-nearest-even
  return (ushortT)(r >> 16);
}
__device__ __forceinline__ uintT pack2(float lo, float hi) {
  return ((uintT)f2bf(hi) << 16) | (uintT)f2bf(lo);
}

union FragU { uint4 u; short8 s; };

// ---------------- K1: X[row,94] @ W[94,64] via bf16 MFMA, 128 rows/block ----
// 4 waves; wave wv owns row-tiles {wv*16, 64+wv*16}, all 4 col-tiles.
// W packed bf16x2 in-block (24 KB raw W is L1-resident across blocks) — the
// separate k_prep dispatch is gone.
__global__ __launch_bounds__(256, 2) void k_feat(
    const float* __restrict__ device_cont, const int* __restrict__ device_cat,
    const float* __restrict__ de0, const float* __restrict__ de1,
    const float* __restrict__ bd,
    const float* __restrict__ combin_cont, const int* __restrict__ combin_cat,
    const int* __restrict__ combin_idx,
    const float* __restrict__ ce0, const float* __restrict__ ce1,
    const float* __restrict__ bc,
    const float* __restrict__ aW,
    const float* __restrict__ Wd, const float* __restrict__ Wc,
    ushortT* __restrict__ h_bf, float* __restrict__ e_d, float* __restrict__ e_c) {
  __shared__ uintT x_s[128 * KP];  // 24,576 B  [row][kpair]
  __shared__ uintT w_s[64 * KP];   // 12,288 B  [col n][kpair]
  __shared__ int   ci_s[128];

  const int tid  = threadIdx.x;
  const int lane = tid & 63;
  const int wv = __builtin_amdgcn_readfirstlane((int)(tid >> 6));
  const int blk = blockIdx.x;
  const bool devp = blk < NDEVG2;
  const int b0 = (devp ? blk : blk - NDEVG2) * 128;

  if (!devp && tid < 128) ci_s[tid] = combin_idx[b0 + tid];

  // ---- stage + pack W: [n][p] bf16x2, n=h*16+o (linear LDS writes) ----
  {
    const float* __restrict__ Ws = devp ? Wd : Wc;
#pragma unroll
    for (int t = 0; t < 12; ++t) {
      const int e = t * 256 + tid;            // 0..3071
      const int n = e / KP, p = e - n * KP;
      const int h = n >> 4, o = n & 15;
      uintT v = 0u;
      if (p < 47) {
        const float lo = Ws[(h * FEAT + 2 * p) * OUTD + o];
        const float hi = Ws[(h * FEAT + 2 * p + 1) * OUTD + o];
        v = pack2(lo, hi);
      }
      w_s[e] = v;
    }
  }
  __syncthreads();  // ci_s visible

  // ---- stage x: cont pairs (128*31 = 3968) ----
  {
    const float* __restrict__ cont = devp ? device_cont : combin_cont;
#pragma unroll 1
    for (int e = tid; e < 128 * 31; e += 256) {
      const int r = e / 31, p = e - r * 31;
      const size_t srow = devp ? (size_t)min(b0 + r, NDEV - 1) : (size_t)ci_s[r];
      const float2 v = *reinterpret_cast<const float2*>(cont + srow * CONTF + 2 * p);
      x_s[r * KP + p] = pack2(v.x, v.y);
    }
  }
  // ---- stage embeddings: all 256 threads, one (row, table) each ----
  {
    const int r = tid >> 1, tb = tid & 1;  // r in 0..127
    const int srow = devp ? min(b0 + r, NDEV - 1) : ci_s[r];
    const int cidx = (devp ? device_cat : combin_cat)[2 * srow + tb];
    const float* __restrict__ ep =
        (tb ? (devp ? de1 : ce1) : (devp ? de0 : ce0)) + (size_t)cidx * EMB;
    uintT* __restrict__ dst = &x_s[r * KP + 31 + tb * 8];
#pragma unroll
    for (int k4 = 0; k4 < 4; ++k4) {
      const float4 v = reinterpret_cast<const float4*>(ep)[k4];
      dst[2 * k4 + 0] = pack2(v.x, v.y);
      dst[2 * k4 + 1] = pack2(v.z, v.w);
    }
  }
  if (tid < 128) x_s[tid * KP + 47] = 0u;         // k = 94,95 zero pad
  __syncthreads();

  // ---- MFMA compute ----
  const int m = lane & 15, q = lane >> 4;
  const float* bias = uniform_ptr(devp ? bd : bc);
  const float* aWl  = uniform_ptr(aW);

  float4v acc[2][NH];
#pragma unroll
  for (int ct = 0; ct < NH; ++ct) {
    const float bv = bias[ct * OUTD + m];
    acc[0][ct] = (float4v){bv, bv, bv, bv};
    acc[1][ct] = (float4v){bv, bv, bv, bv};
  }

  const uintT* xa0 = &x_s[(wv * 16 + m) * KP + q * 4];
  const uintT* xa1 = &x_s[(64 + wv * 16 + m) * KP + q * 4];
#pragma unroll
  for (int c = 0; c < 3; ++c) {                  // K chunks of 32
    FragU af0, af1;
    af0.u = *reinterpret_cast<const uint4*>(xa0 + c * 16);
    af1.u = *reinterpret_cast<const uint4*>(xa1 + c * 16);
#pragma unroll
    for (int ct = 0; ct < NH; ++ct) {
      FragU bf;
      bf.u = *reinterpret_cast<const uint4*>(&w_s[(ct * 16 + m) * KP + c * 16 + q * 4]);
      acc[0][ct] = __builtin_amdgcn_mfma_f32_16x16x32_bf16(af0.s, bf.s, acc[0][ct], 0, 0, 0);
      acc[1][ct] = __builtin_amdgcn_mfma_f32_16x16x32_bf16(af1.s, bf.s, acc[1][ct], 0, 0, 0);
    }
  }

  // ---- epilogue: e logits + h store, per row-tile ----
  const int aoff = devp ? OUTD : 0;
  float* __restrict__ eout = devp ? e_d : e_c;
#pragma unroll
  for (int rt = 0; rt < 2; ++rt) {
    const int rowq = b0 + rt * 64 + wv * 16 + q * 4;  // first of 4 rows
#pragma unroll
    for (int ct = 0; ct < NH; ++ct) {
      const float av = aWl[ct * 2 * OUTD + aoff + m];
      float e0 = acc[rt][ct][0] * av, e1 = acc[rt][ct][1] * av,
            e2 = acc[rt][ct][2] * av, e3 = acc[rt][ct][3] * av;
#pragma unroll
      for (int msk = 1; msk < 16; msk <<= 1) {
        e0 += __shfl_xor(e0, msk);
        e1 += __shfl_xor(e1, msk);
        e2 += __shfl_xor(e2, msk);
        e3 += __shfl_xor(e3, msk);
      }
      if (m == ct) {
        const float ev[4] = {e0, e1, e2, e3};
#pragma unroll
        for (int r = 0; r < 4; ++r)
          if (!devp || rowq + r < NDEV) eout[(size_t)(rowq + r) * NH + ct] = ev[r];
      }
    }
    if (devp) {
#pragma unroll
      for (int ct = 0; ct < NH; ++ct) {
#pragma unroll
        for (int r = 0; r < 4; ++r) {
          if (rowq + r < NDEV)
            h_bf[(size_t)(rowq + r) * HOUT + ct * OUTD + m] = f2bf(acc[rt][ct][r]);
        }
      }
    }
  }
}

// ---------------- K2: attention + fusion + MLP, fused ----------------------
// v2: 2 rows per wave (8 rows/block, grid 1024). W2 (204x64 fp32, 52 KB)
// staged ONCE per block into LDS — kills the per-wave L1-thrashing W2 stream
// of v1 (52 KB > 32 KB L1). All weight loads (W1/W3/W4/w2s) feed two rows.
// LDS 72 KB/block -> 2 blocks/CU (8 waves), rows-in-flight/CU unchanged (16).
// Per-row LDS stays wave-local (wave_barrier); one __syncthreads before
// phase D publishes w2s block-wide.
__global__ __launch_bounds__(256, 2) void k_attn(
    const int* __restrict__ neighbor_idx, const int* __restrict__ device_idx,
    const int* __restrict__ device_cat, const float* __restrict__ device_cont,
    const float* __restrict__ de0, const float* __restrict__ de1,
    const int* __restrict__ combin_idx, const int* __restrict__ combin_cat,
    const float* __restrict__ combin_cont,
    const float* __restrict__ ce0, const float* __restrict__ ce1,
    const ushortT* __restrict__ h_bf, const float* __restrict__ e_d,
    const float* __restrict__ e_c, const float* __restrict__ ab,
    const float* __restrict__ W1, const float* __restrict__ b1,
    const float* __restrict__ W2, const float* __restrict__ b2,
    const float* __restrict__ W3, const float* __restrict__ b3,
    const float* __restrict__ W4, const float* __restrict__ b4,
    float* __restrict__ out) {
  __shared__ __align__(16) float w2s[FUS * 64];   // 52,224 B, [f][col]
  __shared__ __align__(16) float pb[8][NH][68];
  __shared__ __align__(16) int   nb[8][KNBR];
  __shared__ __align__(16) float hb[8][HOUT];
  __shared__ __align__(16) float fusb[8][208];    // fusion row (204 + pad)
  __shared__ __align__(16) float x1b[8][64];

  const int tid  = threadIdx.x;
  const int lane = tid & 63;
  const int wid  = __builtin_amdgcn_readfirstlane((int)(tid >> 6));
  const int rbase = blockIdx.x * 8 + wid * 2;     // global row of r2=0
  const int rl0 = wid * 2, rl1 = rl0 + 1;

  // ---- stage W2 -> LDS (3264 float4, issued early; consumed at phase D) ----
  {
    const float4* __restrict__ src = reinterpret_cast<const float4*>(W2);
    float4* __restrict__ dst = reinterpret_cast<float4*>(w2s);
#pragma unroll
    for (int t = 0; t < 13; ++t) {
      const int i = t * 256 + tid;
      if (i < (FUS * 64) / 4) dst[i] = src[i];
    }
  }

  // ---- phase A: softmax over neighbors (lane = k), both rows ----
  const float4 ab4 = *reinterpret_cast<const float4*>(ab);
#pragma unroll
  for (int r2 = 0; r2 < 2; ++r2) {
    const int b  = rbase + r2;
    const int rl = rl0 + r2;
    const int nk = neighbor_idx[(size_t)b * KNBR + lane];
    const float4 ed4 = *reinterpret_cast<const float4*>(e_d + (size_t)nk * NH);
    const float4 ec4 = *reinterpret_cast<const float4*>(e_c + (size_t)b * NH);

    float v0 = ec4.x + ed4.x + ab4.x;
    float v1 = ec4.y + ed4.y + ab4.y;
    float v2 = ec4.z + ed4.z + ab4.z;
    float v3 = ec4.w + ed4.w + ab4.w;
    v0 = v0 > 0.f ? v0 : ALPHA * v0;
    v1 = v1 > 0.f ? v1 : ALPHA * v1;
    v2 = v2 > 0.f ? v2 : ALPHA * v2;
    v3 = v3 > 0.f ? v3 : ALPHA * v3;

    float m0 = v0, m1 = v1, m2 = v2, m3 = v3;
#pragma unroll
    for (int msk = 1; msk < 64; msk <<= 1) {
      m0 = fmaxf(m0, __shfl_xor(m0, msk));
      m1 = fmaxf(m1, __shfl_xor(m1, msk));
      m2 = fmaxf(m2, __shfl_xor(m2, msk));
      m3 = fmaxf(m3, __shfl_xor(m3, msk));
    }
    float p0 = expf(v0 - m0), p1 = expf(v1 - m1), p2 = expf(v2 - m2), p3 = expf(v3 - m3);
    float s0 = p0, s1 = p1, s2 = p2, s3 = p3;
#pragma unroll
    for (int msk = 1; msk < 64; msk <<= 1) {
      s0 += __shfl_xor(s0, msk);
      s1 += __shfl_xor(s1, msk);
      s2 += __shfl_xor(s2, msk);
      s3 += __shfl_xor(s3, msk);
    }
    p0 /= s0; p1 /= s1; p2 /= s2; p3 /= s3;

    pb[rl][0][lane] = p0;
    pb[rl][1][lane] = p1;
    pb[rl][2][lane] = p2;
    pb[rl][3][lane] = p3;
    nb[rl][lane]    = nk;
  }

  // ---- phase A2: gather fusion features [comb 94 | dev 94], both rows ----
#pragma unroll
  for (int r2 = 0; r2 < 2; ++r2) {
    const int b  = rbase + r2;
    const int rl = rl0 + r2;
    const int ci = combin_idx[b];
    const int cc0 = combin_cat[2 * ci], cc1 = combin_cat[2 * ci + 1];
    const int didx = device_idx[b];
    const int dc0 = device_cat[2 * didx], dc1 = device_cat[2 * didx + 1];
#pragma unroll
    for (int t = 0; t < 3; ++t) {
      const int i = lane + t * 64;
      if (i < 188) {
        float v;
        if (i < 62)       v = combin_cont[(size_t)ci * CONTF + i];
        else if (i < 78)  v = ce0[(size_t)cc0 * EMB + (i - 62)];
        else if (i < 94)  v = ce1[(size_t)cc1 * EMB + (i - 78)];
        else if (i < 156) v = device_cont[(size_t)didx * CONTF + (i - 94)];
        else if (i < 172) v = de0[(size_t)dc0 * EMB + (i - 156)];
        else              v = de1[(size_t)dc1 * EMB + (i - 172)];
        fusb[rl][i] = v;
      }
    }
  }
  __builtin_amdgcn_wave_barrier();

  // ---- phase B: h_bf gather, lane = (q, c8); 16 gathers in flight ----
  {
    const int q = lane >> 3, c8 = lane & 7;
    const int hq = c8 >> 1;
    float a0[8], a1[8];
#pragma unroll
    for (int i = 0; i < 8; ++i) { a0[i] = 0.f; a1[i] = 0.f; }
#pragma unroll
    for (int t = 0; t < 8; ++t) {
      const int k = q * 8 + t;
      const int n0 = nb[rl0][k], n1 = nb[rl1][k];
      const float p0 = pb[rl0][hq][k], p1 = pb[rl1][hq][k];
      const ushort8v h0 =
          *reinterpret_cast<const ushort8v*>(h_bf + (size_t)n0 * HOUT + c8 * 8);
      const ushort8v h1 =
          *reinterpret_cast<const ushort8v*>(h_bf + (size_t)n1 * HOUT + c8 * 8);
#pragma unroll
      for (int i = 0; i < 8; ++i) {
        a0[i] = fmaf(p0, bf2f(h0[i]), a0[i]);
        a1[i] = fmaf(p1, bf2f(h1[i]), a1[i]);
      }
    }
#pragma unroll
    for (int msk = 8; msk < 64; msk <<= 1) {
#pragma unroll
      for (int i = 0; i < 8; ++i) {
        a0[i] += __shfl_xor(a0[i], msk);
        a1[i] += __shfl_xor(a1[i], msk);
      }
    }
    if (q == 0) {
#pragma unroll
      for (int i = 0; i < 8; ++i) {
        a0[i] = a0[i] > 0.f ? a0[i] : expm1f(a0[i]);  // elu
        a1[i] = a1[i] > 0.f ? a1[i] : expm1f(a1[i]);
      }
      float4* hp0 = reinterpret_cast<float4*>(&hb[rl0][c8 * 8]);
      hp0[0] = make_float4(a0[0], a0[1], a0[2], a0[3]);
      hp0[1] = make_float4(a0[4], a0[5], a0[6], a0[7]);
      float4* hp1 = reinterpret_cast<float4*>(&hb[rl1][c8 * 8]);
      hp1[0] = make_float4(a1[0], a1[1], a1[2], a1[3]);
      hp1[1] = make_float4(a1[4], a1[5], a1[6], a1[7]);
    }
  }
  __builtin_amdgcn_wave_barrier();

  // ---- phase C: attn_feats = head_out(64) @ W1(64x16) + b1, both rows ----
  {
    const int j = lane & 15, gg = lane >> 4;
    float pa = 0.f, pc = 0.f;
#pragma unroll
    for (int t = 0; t < 16; ++t) {
      const float w = W1[(gg * 16 + t) * OUTD + j];
      pa = fmaf(hb[rl0][gg * 16 + t], w, pa);
      pc = fmaf(hb[rl1][gg * 16 + t], w, pc);
    }
    pa += __shfl_xor(pa, 16);
    pa += __shfl_xor(pa, 32);
    pc += __shfl_xor(pc, 16);
    pc += __shfl_xor(pc, 32);
    if (lane < 16) {
      const float bb = b1[lane];
      fusb[rl0][188 + lane] = pa + bb;
      fusb[rl1][188 + lane] = pc + bb;
    }
  }
  __builtin_amdgcn_wave_barrier();
  __syncthreads();   // w2s published block-wide (also orders fusb, wave-local)

  // ---- phase D: MLP layer 1 (204 -> 64) from LDS, shared w-reads ----
  float acc0 = b2[lane];
  float acc1 = acc0;
#pragma unroll 4
  for (int f2 = 0; f2 < FUS / 2; ++f2) {
    const float2 u0 = *reinterpret_cast<const float2*>(&fusb[rl0][2 * f2]);
    const float2 u1 = *reinterpret_cast<const float2*>(&fusb[rl1][2 * f2]);
    const float wa = w2s[f2 * 128 + lane];        // conflict-free (2-way)
    const float wb = w2s[f2 * 128 + 64 + lane];
    acc0 = fmaf(u0.y, wb, fmaf(u0.x, wa, acc0));
    acc1 = fmaf(u1.y, wb, fmaf(u1.x, wa, acc1));
  }
  x1b[rl0][lane] = fmaxf(acc0, 0.f);
  x1b[rl1][lane] = fmaxf(acc1, 0.f);
  __builtin_amdgcn_wave_barrier();

  // ---- layers 2+3 + sigmoid, both rows (shared W3/W4 loads) ----
  const int m = lane & 31, rh = lane >> 5;
  float x20 = rh ? 0.f : b3[m];
  float x21 = x20;
#pragma unroll 4
  for (int j = 0; j < 32; ++j) {
    const int jj = rh * 32 + j;
    const float w = W3[jj * 32 + m];
    x20 = fmaf(x1b[rl0][jj], w, x20);
    x21 = fmaf(x1b[rl1][jj], w, x21);
  }
  x20 += __shfl_xor(x20, 32);                     // combine j-halves
  x21 += __shfl_xor(x21, 32);
  const float w4 = W4[m];
  float pL0 = fmaxf(x20, 0.f) * w4;
  float pL1 = fmaxf(x21, 0.f) * w4;
#pragma unroll
  for (int msk = 1; msk < 32; msk <<= 1) {
    pL0 += __shfl_xor(pL0, msk);
    pL1 += __shfl_xor(pL1, msk);
  }
  if (lane == 0) {
    const float bz = b4[0];
    out[rbase]     = 1.f / (1.f + expf(-(pL0 + bz)));
    out[rbase + 1] = 1.f / (1.f + expf(-(pL1 + bz)));
  }
}

extern "C" void kernel_launch(void* const* d_in, const int* in_sizes, int n_in,
                              void* d_out, int out_size, void* d_ws, size_t ws_size,
                              hipStream_t stream) {
  const float* combin_cont  = (const float*)d_in[0];
  const int*   combin_cat   = (const int*)d_in[1];
  const float* device_cont  = (const float*)d_in[2];
  const int*   device_cat   = (const int*)d_in[3];
  const int*   combin_idx   = (const int*)d_in[4];
  const int*   device_idx   = (const int*)d_in[5];
  const int*   neighbor_idx = (const int*)d_in[6];
  const float* ce0 = (const float*)d_in[7];
  const float* ce1 = (const float*)d_in[8];
  const float* de0 = (const float*)d_in[9];
  const float* de1 = (const float*)d_in[10];
  const float* Wc  = (const float*)d_in[11];
  const float* bc  = (const float*)d_in[12];
  const float* Wd  = (const float*)d_in[13];
  const float* bd  = (const float*)d_in[14];
  const float* aW  = (const float*)d_in[15];
  const float* ab  = (const float*)d_in[16];
  const float* W1  = (const float*)d_in[17];
  const float* b1  = (const float*)d_in[18];
  const float* W2  = (const float*)d_in[19];
  const float* b2  = (const float*)d_in[20];
  const float* W3  = (const float*)d_in[21];
  const float* b3  = (const float*)d_in[22];
  const float* W4  = (const float*)d_in[23];
  const float* b4  = (const float*)d_in[24];

  float* ws  = (float*)d_ws;
  ushortT* h_bf = (ushortT*)ws;
  float* e_d = ws + 3200000;
  float* e_c = ws + 3600000;

  k_feat<<<NDEVG2 + NCOMBG2, 256, 0, stream>>>(
      device_cont, device_cat, de0, de1, bd,
      combin_cont, combin_cat, combin_idx, ce0, ce1, bc, aW, Wd, Wc,
      h_bf, e_d, e_c);
  k_attn<<<NBATCH / 8, 256, 0, stream>>>(
      neighbor_idx, device_idx, device_cat, device_cont, de0, de1,
      combin_idx, combin_cat, combin_cont, ce0, ce1,
      h_bf, e_d, e_c, ab, W1, b1, W2, b2, W3, b3, W4, b4, (float*)d_out);
}

// Round 3
// 176.217 us; speedup vs baseline: 1.0387x; 1.0387x over previous
//
#include <hip/hip_runtime.h>
#include <cmath>

#define NDEV   100000
#define NBATCH 8192
#define CONTF  62
#define EMB    16
#define FEAT   94      // 62 + 16 + 16
#define KNBR   64
#define NH     4
#define OUTD   16
#define HOUT   64      // NH*OUTD
#define FUS    204     // 94 + 94 + 16
#define ALPHA  0.2f

#define NDEVG2  782    // ceil(100000/128) row-groups
#define NCOMBG2 64     // 8192/128 row-groups
#define KP      48     // K-pairs incl. zero pad (96 bf16 = 48 uints)

typedef unsigned short ushortT;
typedef unsigned int   uintT;
typedef ushortT ushort8v __attribute__((ext_vector_type(8)));
typedef short   short8  __attribute__((ext_vector_type(8)));
typedef float   float4v __attribute__((ext_vector_type(4)));

// ---------------- workspace layout (float slots) ----------------
// h_bf  : NDEV*64 bf16 = 3,200,000 @ 0   (12.8 MB)
// e_d   : NDEV*4       =   400,000 @ 3,200,000
// e_c   : NBATCH*4     =    32,768 @ 3,600,000

template <typename T>
__device__ __forceinline__ const T* uniform_ptr(const T* p) {
  uint64_t v = (uint64_t)(uintptr_t)p;
  uint32_t lo = __builtin_amdgcn_readfirstlane((uint32_t)v);
  uint32_t hi = __builtin_amdgcn_readfirstlane((uint32_t)(v >> 32));
  return (const T*)(uintptr_t)(((uint64_t)hi << 32) | lo);
}

__device__ __forceinline__ float bf2f(ushortT u) {
  return __uint_as_float(((unsigned int)u) << 16);
}
__device__ __forceinline__ ushortT f2bf(float f) {
  unsigned int i = __float_as_uint(f);
  unsigned int r = i + 0x7FFFu + ((i >> 16) & 1u);  // round-to-nearest-even
  return (ushortT)(r >> 16);
}
__device__ __forceinline__ uintT pack2(float lo, float hi) {
  return ((uintT)f2bf(hi) << 16) | (uintT)f2bf(lo);
}

union FragU { uint4 u; short8 s; };

// ---------------- K1: X[row,94] @ W[94,64] via bf16 MFMA, 128 rows/block ----
// 4 waves; wave wv owns row-tiles {wv*16, 64+wv*16}, all 4 col-tiles.
// W packed bf16x2 in-block (24 KB raw W is L1/L2-resident across blocks).
__global__ __launch_bounds__(256, 2) void k_feat(
    const float* __restrict__ device_cont, const int* __restrict__ device_cat,
    const float* __restrict__ de0, const float* __restrict__ de1,
    const float* __restrict__ bd,
    const float* __restrict__ combin_cont, const int* __restrict__ combin_cat,
    const int* __restrict__ combin_idx,
    const float* __restrict__ ce0, const float* __restrict__ ce1,
    const float* __restrict__ bc,
    const float* __restrict__ aW,
    const float* __restrict__ Wd, const float* __restrict__ Wc,
    ushortT* __restrict__ h_bf, float* __restrict__ e_d, float* __restrict__ e_c) {
  __shared__ uintT x_s[128 * KP];  // 24,576 B  [row][kpair]
  __shared__ uintT w_s[64 * KP];   // 12,288 B  [col n][kpair]
  __shared__ int   ci_s[128];

  const int tid  = threadIdx.x;
  const int lane = tid & 63;
  const int wv = __builtin_amdgcn_readfirstlane((int)(tid >> 6));
  const int blk = blockIdx.x;
  const bool devp = blk < NDEVG2;
  const int b0 = (devp ? blk : blk - NDEVG2) * 128;

  if (!devp && tid < 128) ci_s[tid] = combin_idx[b0 + tid];

  // ---- stage + pack W: [n][p] bf16x2, n=h*16+o (linear LDS writes) ----
  {
    const float* __restrict__ Ws = devp ? Wd : Wc;
#pragma unroll
    for (int t = 0; t < 12; ++t) {
      const int e = t * 256 + tid;            // 0..3071
      const int n = e / KP, p = e - n * KP;
      const int h = n >> 4, o = n & 15;
      uintT v = 0u;
      if (p < 47) {
        const float lo = Ws[(h * FEAT + 2 * p) * OUTD + o];
        const float hi = Ws[(h * FEAT + 2 * p + 1) * OUTD + o];
        v = pack2(lo, hi);
      }
      w_s[e] = v;
    }
  }
  __syncthreads();  // ci_s visible

  // ---- stage x: cont pairs (128*31 = 3968) ----
  {
    const float* __restrict__ cont = devp ? device_cont : combin_cont;
#pragma unroll 1
    for (int e = tid; e < 128 * 31; e += 256) {
      const int r = e / 31, p = e - r * 31;
      const size_t srow = devp ? (size_t)min(b0 + r, NDEV - 1) : (size_t)ci_s[r];
      const float2 v = *reinterpret_cast<const float2*>(cont + srow * CONTF + 2 * p);
      x_s[r * KP + p] = pack2(v.x, v.y);
    }
  }
  // ---- stage embeddings: all 256 threads, one (row, table) each ----
  {
    const int r = tid >> 1, tb = tid & 1;  // r in 0..127
    const int srow = devp ? min(b0 + r, NDEV - 1) : ci_s[r];
    const int cidx = (devp ? device_cat : combin_cat)[2 * srow + tb];
    const float* __restrict__ ep =
        (tb ? (devp ? de1 : ce1) : (devp ? de0 : ce0)) + (size_t)cidx * EMB;
    uintT* __restrict__ dst = &x_s[r * KP + 31 + tb * 8];
#pragma unroll
    for (int k4 = 0; k4 < 4; ++k4) {
      const float4 v = reinterpret_cast<const float4*>(ep)[k4];
      dst[2 * k4 + 0] = pack2(v.x, v.y);
      dst[2 * k4 + 1] = pack2(v.z, v.w);
    }
  }
  if (tid < 128) x_s[tid * KP + 47] = 0u;         // k = 94,95 zero pad
  __syncthreads();

  // ---- MFMA compute ----
  const int m = lane & 15, q = lane >> 4;
  const float* bias = uniform_ptr(devp ? bd : bc);
  const float* aWl  = uniform_ptr(aW);

  float4v acc[2][NH];
#pragma unroll
  for (int ct = 0; ct < NH; ++ct) {
    const float bv = bias[ct * OUTD + m];
    acc[0][ct] = (float4v){bv, bv, bv, bv};
    acc[1][ct] = (float4v){bv, bv, bv, bv};
  }

  const uintT* xa0 = &x_s[(wv * 16 + m) * KP + q * 4];
  const uintT* xa1 = &x_s[(64 + wv * 16 + m) * KP + q * 4];
#pragma unroll
  for (int c = 0; c < 3; ++c) {                  // K chunks of 32
    FragU af0, af1;
    af0.u = *reinterpret_cast<const uint4*>(xa0 + c * 16);
    af1.u = *reinterpret_cast<const uint4*>(xa1 + c * 16);
#pragma unroll
    for (int ct = 0; ct < NH; ++ct) {
      FragU bf;
      bf.u = *reinterpret_cast<const uint4*>(&w_s[(ct * 16 + m) * KP + c * 16 + q * 4]);
      acc[0][ct] = __builtin_amdgcn_mfma_f32_16x16x32_bf16(af0.s, bf.s, acc[0][ct], 0, 0, 0);
      acc[1][ct] = __builtin_amdgcn_mfma_f32_16x16x32_bf16(af1.s, bf.s, acc[1][ct], 0, 0, 0);
    }
  }

  // ---- epilogue: e logits + h store, per row-tile ----
  const int aoff = devp ? OUTD : 0;
  float* __restrict__ eout = devp ? e_d : e_c;
#pragma unroll
  for (int rt = 0; rt < 2; ++rt) {
    const int rowq = b0 + rt * 64 + wv * 16 + q * 4;  // first of 4 rows
#pragma unroll
    for (int ct = 0; ct < NH; ++ct) {
      const float av = aWl[ct * 2 * OUTD + aoff + m];
      float e0 = acc[rt][ct][0] * av, e1 = acc[rt][ct][1] * av,
            e2 = acc[rt][ct][2] * av, e3 = acc[rt][ct][3] * av;
#pragma unroll
      for (int msk = 1; msk < 16; msk <<= 1) {
        e0 += __shfl_xor(e0, msk);
        e1 += __shfl_xor(e1, msk);
        e2 += __shfl_xor(e2, msk);
        e3 += __shfl_xor(e3, msk);
      }
      if (m == ct) {
        const float ev[4] = {e0, e1, e2, e3};
#pragma unroll
        for (int r = 0; r < 4; ++r)
          if (!devp || rowq + r < NDEV) eout[(size_t)(rowq + r) * NH + ct] = ev[r];
      }
    }
    if (devp) {
#pragma unroll
      for (int ct = 0; ct < NH; ++ct) {
#pragma unroll
        for (int r = 0; r < 4; ++r) {
          if (rowq + r < NDEV)
            h_bf[(size_t)(rowq + r) * HOUT + ct * OUTD + m] = f2bf(acc[rt][ct][r]);
        }
      }
    }
  }
}

// ---------------- K2: attention + fusion + MLP, fused (one wave = one row) --
// v3: back to 1 row/wave, small LDS (9.75 KB) -> 4 blocks/CU residency
// (v2's 52 KB w2s slab halved residency and regressed: latency-bound kernel).
// New: (a) h_bf gather issued EARLY via __shfl-derived neighbor indices —
// the 8x16B loads are in flight during the softmax shuffle-reduce (T14);
// (b) softmax drops the max-subtract (logits bounded ~|3|, exp fp32-safe;
// halves the butterfly count); (c) nb LDS buffer deleted (indices via shfl).
__global__ __launch_bounds__(256, 4) void k_attn(
    const int* __restrict__ neighbor_idx, const int* __restrict__ device_idx,
    const int* __restrict__ device_cat, const float* __restrict__ device_cont,
    const float* __restrict__ de0, const float* __restrict__ de1,
    const int* __restrict__ combin_idx, const int* __restrict__ combin_cat,
    const float* __restrict__ combin_cont,
    const float* __restrict__ ce0, const float* __restrict__ ce1,
    const ushortT* __restrict__ h_bf, const float* __restrict__ e_d,
    const float* __restrict__ e_c, const float* __restrict__ ab,
    const float* __restrict__ W1, const float* __restrict__ b1,
    const float* __restrict__ W2, const float* __restrict__ b2,
    const float* __restrict__ W3, const float* __restrict__ b3,
    const float* __restrict__ W4, const float* __restrict__ b4,
    float* __restrict__ out) {
  __shared__ __align__(16) float pb[4][NH][68];
  __shared__ __align__(16) float hb[4][HOUT];
  __shared__ __align__(16) float fusb[4][208];   // fusion row (204 + pad)
  __shared__ __align__(16) float x1b[4][64];

  const int lane = threadIdx.x & 63;
  const int wid  = __builtin_amdgcn_readfirstlane((int)(threadIdx.x >> 6));
  const int b    = blockIdx.x * 4 + wid;

  // ---- phase A0: neighbor index + e gathers issued first ----
  const int nk = neighbor_idx[(size_t)b * KNBR + lane];
  const float4 ed4 = *reinterpret_cast<const float4*>(e_d + (size_t)nk * NH);
  const float4 ec4 = *reinterpret_cast<const float4*>(e_c + (size_t)b * NH);
  const float4 ab4 = *reinterpret_cast<const float4*>(ab);

  // ---- phase A1: EARLY h_bf prefetch for this lane's phase-B slice.
  // Lane (q,c8) consumes neighbors q*8..q*8+7 at cols c8*8..c8*8+7; pull the
  // indices from the owning lanes' registers (no LDS round-trip) and issue
  // all 8 16B loads now — they complete under the softmax below.
  const int q = lane >> 3, c8 = lane & 7;
  ushort8v hpre[8];
#pragma unroll
  for (int t = 0; t < 8; ++t) {
    const int nt = __shfl(nk, q * 8 + t);
    hpre[t] = *reinterpret_cast<const ushort8v*>(h_bf + (size_t)nt * HOUT + c8 * 8);
  }

  // ---- phase A2: gather fusion features [comb 94 | dev 94] into LDS ----
  const int ci = combin_idx[b];
  const int cc0 = combin_cat[2 * ci], cc1 = combin_cat[2 * ci + 1];
  const int didx = device_idx[b];
  const int dc0 = device_cat[2 * didx], dc1 = device_cat[2 * didx + 1];
#pragma unroll
  for (int t = 0; t < 3; ++t) {
    const int i = lane + t * 64;
    if (i < 188) {
      float v;
      if (i < 62)       v = combin_cont[(size_t)ci * CONTF + i];
      else if (i < 78)  v = ce0[(size_t)cc0 * EMB + (i - 62)];
      else if (i < 94)  v = ce1[(size_t)cc1 * EMB + (i - 78)];
      else if (i < 156) v = device_cont[(size_t)didx * CONTF + (i - 94)];
      else if (i < 172) v = de0[(size_t)dc0 * EMB + (i - 156)];
      else              v = de1[(size_t)dc1 * EMB + (i - 172)];
      fusb[wid][i] = v;
    }
  }

  // ---- phase A3: softmax over neighbors (lane = k), no max-subtract ----
  float v0 = ec4.x + ed4.x + ab4.x;
  float v1 = ec4.y + ed4.y + ab4.y;
  float v2 = ec4.z + ed4.z + ab4.z;
  float v3 = ec4.w + ed4.w + ab4.w;
  v0 = v0 > 0.f ? v0 : ALPHA * v0;
  v1 = v1 > 0.f ? v1 : ALPHA * v1;
  v2 = v2 > 0.f ? v2 : ALPHA * v2;
  v3 = v3 > 0.f ? v3 : ALPHA * v3;

  float p0 = expf(v0), p1 = expf(v1), p2 = expf(v2), p3 = expf(v3);
  float s0 = p0, s1 = p1, s2 = p2, s3 = p3;
#pragma unroll
  for (int msk = 1; msk < 64; msk <<= 1) {
    s0 += __shfl_xor(s0, msk);
    s1 += __shfl_xor(s1, msk);
    s2 += __shfl_xor(s2, msk);
    s3 += __shfl_xor(s3, msk);
  }
  p0 /= s0; p1 /= s1; p2 /= s2; p3 /= s3;

  pb[wid][0][lane] = p0;
  pb[wid][1][lane] = p1;
  pb[wid][2][lane] = p2;
  pb[wid][3][lane] = p3;
  __builtin_amdgcn_wave_barrier();

  // ---- phase B: weighted sum from prefetched h regs, lane = (q, c8) ----
  {
    const int hq = c8 >> 1;
    float a[8];
#pragma unroll
    for (int i = 0; i < 8; ++i) a[i] = 0.f;
#pragma unroll
    for (int t = 0; t < 8; ++t) {
      const float p = pb[wid][hq][q * 8 + t];
#pragma unroll
      for (int i = 0; i < 8; ++i) a[i] = fmaf(p, bf2f(hpre[t][i]), a[i]);
    }
#pragma unroll
    for (int msk = 8; msk < 64; msk <<= 1) {
#pragma unroll
      for (int i = 0; i < 8; ++i) a[i] += __shfl_xor(a[i], msk);
    }
    if (q == 0) {
#pragma unroll
      for (int i = 0; i < 8; ++i) a[i] = a[i] > 0.f ? a[i] : expm1f(a[i]);  // elu
      float4* hp = reinterpret_cast<float4*>(&hb[wid][c8 * 8]);
      hp[0] = make_float4(a[0], a[1], a[2], a[3]);
      hp[1] = make_float4(a[4], a[5], a[6], a[7]);
    }
  }
  __builtin_amdgcn_wave_barrier();

  // ---- phase C: attn_feats = head_out(64) @ W1(64x16) + b1 -> fusb[188..] --
  {
    const int j = lane & 15, gg = lane >> 4;
    float part = 0.f;
#pragma unroll
    for (int t = 0; t < 16; ++t)
      part = fmaf(hb[wid][gg * 16 + t], W1[(gg * 16 + t) * OUTD + j], part);
    part += __shfl_xor(part, 16);
    part += __shfl_xor(part, 32);
    if (lane < 16) fusb[wid][188 + lane] = part + b1[lane];
  }
  __builtin_amdgcn_wave_barrier();

  // ---- phase D: MLP layer 1 (204 -> 64), lane = output col ----
  float acc = b2[lane];
#pragma unroll 4
  for (int f = 0; f < FUS; ++f)
    acc = fmaf(fusb[wid][f], W2[f * 64 + lane], acc);  // ds broadcast + coalesced
  x1b[wid][lane] = fmaxf(acc, 0.f);
  __builtin_amdgcn_wave_barrier();

  // ---- layers 2+3 + sigmoid ----
  const int m = lane & 31, rh = lane >> 5;
  float x2 = rh ? 0.f : b3[m];
#pragma unroll 4
  for (int j = 0; j < 32; ++j) {
    const int jj = rh * 32 + j;
    x2 = fmaf(x1b[wid][jj], W3[jj * 32 + m], x2);
  }
  x2 += __shfl_xor(x2, 32);                      // combine j-halves
  float pL3 = fmaxf(x2, 0.f) * W4[m];
#pragma unroll
  for (int msk = 1; msk < 32; msk <<= 1) pL3 += __shfl_xor(pL3, msk);
  if (lane == 0) {
    const float z = pL3 + b4[0];
    out[b] = 1.f / (1.f + expf(-z));
  }
}

extern "C" void kernel_launch(void* const* d_in, const int* in_sizes, int n_in,
                              void* d_out, int out_size, void* d_ws, size_t ws_size,
                              hipStream_t stream) {
  const float* combin_cont  = (const float*)d_in[0];
  const int*   combin_cat   = (const int*)d_in[1];
  const float* device_cont  = (const float*)d_in[2];
  const int*   device_cat   = (const int*)d_in[3];
  const int*   combin_idx   = (const int*)d_in[4];
  const int*   device_idx   = (const int*)d_in[5];
  const int*   neighbor_idx = (const int*)d_in[6];
  const float* ce0 = (const float*)d_in[7];
  const float* ce1 = (const float*)d_in[8];
  const float* de0 = (const float*)d_in[9];
  const float* de1 = (const float*)d_in[10];
  const float* Wc  = (const float*)d_in[11];
  const float* bc  = (const float*)d_in[12];
  const float* Wd  = (const float*)d_in[13];
  const float* bd  = (const float*)d_in[14];
  const float* aW  = (const float*)d_in[15];
  const float* ab  = (const float*)d_in[16];
  const float* W1  = (const float*)d_in[17];
  const float* b1  = (const float*)d_in[18];
  const float* W2  = (const float*)d_in[19];
  const float* b2  = (const float*)d_in[20];
  const float* W3  = (const float*)d_in[21];
  const float* b3  = (const float*)d_in[22];
  const float* W4  = (const float*)d_in[23];
  const float* b4  = (const float*)d_in[24];

  float* ws  = (float*)d_ws;
  ushortT* h_bf = (ushortT*)ws;
  float* e_d = ws + 3200000;
  float* e_c = ws + 3600000;

  k_feat<<<NDEVG2 + NCOMBG2, 256, 0, stream>>>(
      device_cont, device_cat, de0, de1, bd,
      combin_cont, combin_cat, combin_idx, ce0, ce1, bc, aW, Wd, Wc,
      h_bf, e_d, e_c);
  k_attn<<<2048, 256, 0, stream>>>(
      neighbor_idx, device_idx, device_cat, device_cont, de0, de1,
      combin_idx, combin_cat, combin_cont, ce0, ce1,
      h_bf, e_d, e_c, ab, W1, b1, W2, b2, W3, b3, W4, b4, (float*)d_out);
}

// Round 4
// 169.583 us; speedup vs baseline: 1.0794x; 1.0391x over previous
//
#include <hip/hip_runtime.h>
#include <cmath>

#define NDEV   100000
#define NBATCH 8192
#define CONTF  62
#define EMB    16
#define FEAT   94      // 62 + 16 + 16
#define KNBR   64
#define NH     4
#define OUTD   16
#define HOUT   64      // NH*OUTD
#define FUS    204     // 94 + 94 + 16
#define ALPHA  0.2f

#define NDEVG2  782    // ceil(100000/128) row-groups
#define NCOMBG2 64     // 8192/128 row-groups
#define KP      48     // K-pairs incl. zero pad (96 bf16 = 48 uints)

typedef unsigned short ushortT;
typedef unsigned int   uintT;
typedef ushortT ushort8v __attribute__((ext_vector_type(8)));
typedef short   short8  __attribute__((ext_vector_type(8)));
typedef float   float4v __attribute__((ext_vector_type(4)));

// ---------------- workspace layout (float slots) ----------------
// h_bf  : NDEV*64 bf16 = 3,200,000 @ 0   (12.8 MB)
// e_d   : NDEV*4       =   400,000 @ 3,200,000
// e_c   : NBATCH*4     =    32,768 @ 3,600,000
// wpack : 2*64*48 uint =     6,144 @ 3,632,768   (bf16x2-packed W^T, dev|comb)

template <typename T>
__device__ __forceinline__ const T* uniform_ptr(const T* p) {
  uint64_t v = (uint64_t)(uintptr_t)p;
  uint32_t lo = __builtin_amdgcn_readfirstlane((uint32_t)v);
  uint32_t hi = __builtin_amdgcn_readfirstlane((uint32_t)(v >> 32));
  return (const T*)(uintptr_t)(((uint64_t)hi << 32) | lo);
}

__device__ __forceinline__ float bf2f(ushortT u) {
  return __uint_as_float(((unsigned int)u) << 16);
}
__device__ __forceinline__ ushortT f2bf(float f) {
  unsigned int i = __float_as_uint(f);
  unsigned int r = i + 0x7FFFu + ((i >> 16) & 1u);  // round-to-nearest-even
  return (ushortT)(r >> 16);
}
__device__ __forceinline__ uintT pack2(float lo, float hi) {
  return ((uintT)f2bf(hi) << 16) | (uintT)f2bf(lo);
}

union FragU { uint4 u; short8 s; };

// ---------------- K0: pack W^T -> bf16x2 once (layout [n][p], n=h*16+o) -----
__global__ __launch_bounds__(256) void k_prep(
    const float* __restrict__ Wd, const float* __restrict__ Wc,
    uintT* __restrict__ wpack) {
  const int e = blockIdx.x * 256 + threadIdx.x;   // 0..6143
  if (e >= 2 * 64 * KP) return;
  const bool dev = e < 64 * KP;
  const int i = dev ? e : e - 64 * KP;
  const int n = i / KP, p = i - n * KP;
  const int h = n >> 4, o = n & 15;
  const float* __restrict__ Ws = dev ? Wd : Wc;
  uintT v = 0u;
  if (p < 47) {
    const float lo = Ws[(h * FEAT + 2 * p) * OUTD + o];
    const float hi = Ws[(h * FEAT + 2 * p + 1) * OUTD + o];
    v = pack2(lo, hi);
  }
  wpack[e] = v;
}

// ---------------- K1: X[row,94] @ W[94,64] via bf16 MFMA, 128 rows/block ----
// 4 waves; wave wv owns row-tiles {wv*16, 64+wv*16}, all 4 col-tiles.
// W staged once per block (prepacked); B-frags reused across both row-tiles.
__global__ __launch_bounds__(256, 2) void k_feat(
    const float* __restrict__ device_cont, const int* __restrict__ device_cat,
    const float* __restrict__ de0, const float* __restrict__ de1,
    const float* __restrict__ bd,
    const float* __restrict__ combin_cont, const int* __restrict__ combin_cat,
    const int* __restrict__ combin_idx,
    const float* __restrict__ ce0, const float* __restrict__ ce1,
    const float* __restrict__ bc,
    const float* __restrict__ aW, const uintT* __restrict__ wpack,
    ushortT* __restrict__ h_bf, float* __restrict__ e_d, float* __restrict__ e_c) {
  __shared__ uintT x_s[128 * KP];  // 24,576 B  [row][kpair]
  __shared__ uintT w_s[64 * KP];   // 12,288 B  [col n][kpair]
  __shared__ int   ci_s[128];

  const int tid  = threadIdx.x;
  const int lane = tid & 63;
  const int wv = __builtin_amdgcn_readfirstlane((int)(tid >> 6));
  const int blk = blockIdx.x;
  const bool devp = blk < NDEVG2;
  const int b0 = (devp ? blk : blk - NDEVG2) * 128;

  if (!devp && tid < 128) ci_s[tid] = combin_idx[b0 + tid];

  // ---- stage W: linear uint4 copy of the prepacked slab (768 uint4) ----
  {
    const uint4* __restrict__ wp =
        reinterpret_cast<const uint4*>(wpack + (devp ? 0 : 64 * KP));
#pragma unroll
    for (int t = 0; t < 3; ++t)
      reinterpret_cast<uint4*>(w_s)[t * 256 + tid] = wp[t * 256 + tid];
  }
  __syncthreads();  // ci_s visible

  // ---- stage x: cont pairs (128*31 = 3968) ----
  {
    const float* __restrict__ cont = devp ? device_cont : combin_cont;
#pragma unroll 1
    for (int e = tid; e < 128 * 31; e += 256) {
      const int r = e / 31, p = e - r * 31;
      const size_t srow = devp ? (size_t)min(b0 + r, NDEV - 1) : (size_t)ci_s[r];
      const float2 v = *reinterpret_cast<const float2*>(cont + srow * CONTF + 2 * p);
      x_s[r * KP + p] = pack2(v.x, v.y);
    }
  }
  // ---- stage embeddings: all 256 threads, one (row, table) each ----
  {
    const int r = tid >> 1, tb = tid & 1;  // r in 0..127
    const int srow = devp ? min(b0 + r, NDEV - 1) : ci_s[r];
    const int cidx = (devp ? device_cat : combin_cat)[2 * srow + tb];
    const float* __restrict__ ep =
        (tb ? (devp ? de1 : ce1) : (devp ? de0 : ce0)) + (size_t)cidx * EMB;
    uintT* __restrict__ dst = &x_s[r * KP + 31 + tb * 8];
#pragma unroll
    for (int k4 = 0; k4 < 4; ++k4) {
      const float4 v = reinterpret_cast<const float4*>(ep)[k4];
      dst[2 * k4 + 0] = pack2(v.x, v.y);
      dst[2 * k4 + 1] = pack2(v.z, v.w);
    }
  }
  if (tid < 128) x_s[tid * KP + 47] = 0u;         // k = 94,95 zero pad
  __syncthreads();

  // ---- MFMA compute ----
  const int m = lane & 15, q = lane >> 4;
  const float* bias = uniform_ptr(devp ? bd : bc);
  const float* aWl  = uniform_ptr(aW);

  float4v acc[2][NH];
#pragma unroll
  for (int ct = 0; ct < NH; ++ct) {
    const float bv = bias[ct * OUTD + m];
    acc[0][ct] = (float4v){bv, bv, bv, bv};
    acc[1][ct] = (float4v){bv, bv, bv, bv};
  }

  const uintT* xa0 = &x_s[(wv * 16 + m) * KP + q * 4];
  const uintT* xa1 = &x_s[(64 + wv * 16 + m) * KP + q * 4];
#pragma unroll
  for (int c = 0; c < 3; ++c) {                  // K chunks of 32
    FragU af0, af1;
    af0.u = *reinterpret_cast<const uint4*>(xa0 + c * 16);
    af1.u = *reinterpret_cast<const uint4*>(xa1 + c * 16);
#pragma unroll
    for (int ct = 0; ct < NH; ++ct) {
      FragU bf;
      bf.u = *reinterpret_cast<const uint4*>(&w_s[(ct * 16 + m) * KP + c * 16 + q * 4]);
      acc[0][ct] = __builtin_amdgcn_mfma_f32_16x16x32_bf16(af0.s, bf.s, acc[0][ct], 0, 0, 0);
      acc[1][ct] = __builtin_amdgcn_mfma_f32_16x16x32_bf16(af1.s, bf.s, acc[1][ct], 0, 0, 0);
    }
  }

  // ---- epilogue: e logits + h store, per row-tile ----
  const int aoff = devp ? OUTD : 0;
  float* __restrict__ eout = devp ? e_d : e_c;
#pragma unroll
  for (int rt = 0; rt < 2; ++rt) {
    const int rowq = b0 + rt * 64 + wv * 16 + q * 4;  // first of 4 rows
#pragma unroll
    for (int ct = 0; ct < NH; ++ct) {
      const float av = aWl[ct * 2 * OUTD + aoff + m];
      float e0 = acc[rt][ct][0] * av, e1 = acc[rt][ct][1] * av,
            e2 = acc[rt][ct][2] * av, e3 = acc[rt][ct][3] * av;
#pragma unroll
      for (int msk = 1; msk < 16; msk <<= 1) {
        e0 += __shfl_xor(e0, msk);
        e1 += __shfl_xor(e1, msk);
        e2 += __shfl_xor(e2, msk);
        e3 += __shfl_xor(e3, msk);
      }
      if (m == ct) {
        const float ev[4] = {e0, e1, e2, e3};
#pragma unroll
        for (int r = 0; r < 4; ++r)
          if (!devp || rowq + r < NDEV) eout[(size_t)(rowq + r) * NH + ct] = ev[r];
      }
    }
    if (devp) {
#pragma unroll
      for (int ct = 0; ct < NH; ++ct) {
#pragma unroll
        for (int r = 0; r < 4; ++r) {
          if (rowq + r < NDEV)
            h_bf[(size_t)(rowq + r) * HOUT + ct * OUTD + m] = f2bf(acc[rt][ct][r]);
        }
      }
    }
  }
}

// ---------------- K2: attention + fusion + MLP, fused (one wave = one row) --
// v3's k_attn unchanged: 1 row/wave, 9.75 KB LDS, 4 blocks/CU; early
// __shfl-indexed h_bf prefetch hides L3 latency under softmax; softmax
// without max-subtract (logits bounded); no nb LDS buffer.
__global__ __launch_bounds__(256, 4) void k_attn(
    const int* __restrict__ neighbor_idx, const int* __restrict__ device_idx,
    const int* __restrict__ device_cat, const float* __restrict__ device_cont,
    const float* __restrict__ de0, const float* __restrict__ de1,
    const int* __restrict__ combin_idx, const int* __restrict__ combin_cat,
    const float* __restrict__ combin_cont,
    const float* __restrict__ ce0, const float* __restrict__ ce1,
    const ushortT* __restrict__ h_bf, const float* __restrict__ e_d,
    const float* __restrict__ e_c, const float* __restrict__ ab,
    const float* __restrict__ W1, const float* __restrict__ b1,
    const float* __restrict__ W2, const float* __restrict__ b2,
    const float* __restrict__ W3, const float* __restrict__ b3,
    const float* __restrict__ W4, const float* __restrict__ b4,
    float* __restrict__ out) {
  __shared__ __align__(16) float pb[4][NH][68];
  __shared__ __align__(16) float hb[4][HOUT];
  __shared__ __align__(16) float fusb[4][208];   // fusion row (204 + pad)
  __shared__ __align__(16) float x1b[4][64];

  const int lane = threadIdx.x & 63;
  const int wid  = __builtin_amdgcn_readfirstlane((int)(threadIdx.x >> 6));
  const int b    = blockIdx.x * 4 + wid;

  // ---- phase A0: neighbor index + e gathers issued first ----
  const int nk = neighbor_idx[(size_t)b * KNBR + lane];
  const float4 ed4 = *reinterpret_cast<const float4*>(e_d + (size_t)nk * NH);
  const float4 ec4 = *reinterpret_cast<const float4*>(e_c + (size_t)b * NH);
  const float4 ab4 = *reinterpret_cast<const float4*>(ab);

  // ---- phase A1: EARLY h_bf prefetch for this lane's phase-B slice ----
  const int q = lane >> 3, c8 = lane & 7;
  ushort8v hpre[8];
#pragma unroll
  for (int t = 0; t < 8; ++t) {
    const int nt = __shfl(nk, q * 8 + t);
    hpre[t] = *reinterpret_cast<const ushort8v*>(h_bf + (size_t)nt * HOUT + c8 * 8);
  }

  // ---- phase A2: gather fusion features [comb 94 | dev 94] into LDS ----
  const int ci = combin_idx[b];
  const int cc0 = combin_cat[2 * ci], cc1 = combin_cat[2 * ci + 1];
  const int didx = device_idx[b];
  const int dc0 = device_cat[2 * didx], dc1 = device_cat[2 * didx + 1];
#pragma unroll
  for (int t = 0; t < 3; ++t) {
    const int i = lane + t * 64;
    if (i < 188) {
      float v;
      if (i < 62)       v = combin_cont[(size_t)ci * CONTF + i];
      else if (i < 78)  v = ce0[(size_t)cc0 * EMB + (i - 62)];
      else if (i < 94)  v = ce1[(size_t)cc1 * EMB + (i - 78)];
      else if (i < 156) v = device_cont[(size_t)didx * CONTF + (i - 94)];
      else if (i < 172) v = de0[(size_t)dc0 * EMB + (i - 156)];
      else              v = de1[(size_t)dc1 * EMB + (i - 172)];
      fusb[wid][i] = v;
    }
  }

  // ---- phase A3: softmax over neighbors (lane = k), no max-subtract ----
  float v0 = ec4.x + ed4.x + ab4.x;
  float v1 = ec4.y + ed4.y + ab4.y;
  float v2 = ec4.z + ed4.z + ab4.z;
  float v3 = ec4.w + ed4.w + ab4.w;
  v0 = v0 > 0.f ? v0 : ALPHA * v0;
  v1 = v1 > 0.f ? v1 : ALPHA * v1;
  v2 = v2 > 0.f ? v2 : ALPHA * v2;
  v3 = v3 > 0.f ? v3 : ALPHA * v3;

  float p0 = expf(v0), p1 = expf(v1), p2 = expf(v2), p3 = expf(v3);
  float s0 = p0, s1 = p1, s2 = p2, s3 = p3;
#pragma unroll
  for (int msk = 1; msk < 64; msk <<= 1) {
    s0 += __shfl_xor(s0, msk);
    s1 += __shfl_xor(s1, msk);
    s2 += __shfl_xor(s2, msk);
    s3 += __shfl_xor(s3, msk);
  }
  p0 /= s0; p1 /= s1; p2 /= s2; p3 /= s3;

  pb[wid][0][lane] = p0;
  pb[wid][1][lane] = p1;
  pb[wid][2][lane] = p2;
  pb[wid][3][lane] = p3;
  __builtin_amdgcn_wave_barrier();

  // ---- phase B: weighted sum from prefetched h regs, lane = (q, c8) ----
  {
    const int hq = c8 >> 1;
    float a[8];
#pragma unroll
    for (int i = 0; i < 8; ++i) a[i] = 0.f;
#pragma unroll
    for (int t = 0; t < 8; ++t) {
      const float p = pb[wid][hq][q * 8 + t];
#pragma unroll
      for (int i = 0; i < 8; ++i) a[i] = fmaf(p, bf2f(hpre[t][i]), a[i]);
    }
#pragma unroll
    for (int msk = 8; msk < 64; msk <<= 1) {
#pragma unroll
      for (int i = 0; i < 8; ++i) a[i] += __shfl_xor(a[i], msk);
    }
    if (q == 0) {
#pragma unroll
      for (int i = 0; i < 8; ++i) a[i] = a[i] > 0.f ? a[i] : expm1f(a[i]);  // elu
      float4* hp = reinterpret_cast<float4*>(&hb[wid][c8 * 8]);
      hp[0] = make_float4(a[0], a[1], a[2], a[3]);
      hp[1] = make_float4(a[4], a[5], a[6], a[7]);
    }
  }
  __builtin_amdgcn_wave_barrier();

  // ---- phase C: attn_feats = head_out(64) @ W1(64x16) + b1 -> fusb[188..] --
  {
    const int j = lane & 15, gg = lane >> 4;
    float part = 0.f;
#pragma unroll
    for (int t = 0; t < 16; ++t)
      part = fmaf(hb[wid][gg * 16 + t], W1[(gg * 16 + t) * OUTD + j], part);
    part += __shfl_xor(part, 16);
    part += __shfl_xor(part, 32);
    if (lane < 16) fusb[wid][188 + lane] = part + b1[lane];
  }
  __builtin_amdgcn_wave_barrier();

  // ---- phase D: MLP layer 1 (204 -> 64), lane = output col ----
  float acc = b2[lane];
#pragma unroll 4
  for (int f = 0; f < FUS; ++f)
    acc = fmaf(fusb[wid][f], W2[f * 64 + lane], acc);  // ds broadcast + coalesced
  x1b[wid][lane] = fmaxf(acc, 0.f);
  __builtin_amdgcn_wave_barrier();

  // ---- layers 2+3 + sigmoid ----
  const int m = lane & 31, rh = lane >> 5;
  float x2 = rh ? 0.f : b3[m];
#pragma unroll 4
  for (int j = 0; j < 32; ++j) {
    const int jj = rh * 32 + j;
    x2 = fmaf(x1b[wid][jj], W3[jj * 32 + m], x2);
  }
  x2 += __shfl_xor(x2, 32);                      // combine j-halves
  float pL3 = fmaxf(x2, 0.f) * W4[m];
#pragma unroll
  for (int msk = 1; msk < 32; msk <<= 1) pL3 += __shfl_xor(pL3, msk);
  if (lane == 0) {
    const float z = pL3 + b4[0];
    out[b] = 1.f / (1.f + expf(-z));
  }
}

extern "C" void kernel_launch(void* const* d_in, const int* in_sizes, int n_in,
                              void* d_out, int out_size, void* d_ws, size_t ws_size,
                              hipStream_t stream) {
  const float* combin_cont  = (const float*)d_in[0];
  const int*   combin_cat   = (const int*)d_in[1];
  const float* device_cont  = (const float*)d_in[2];
  const int*   device_cat   = (const int*)d_in[3];
  const int*   combin_idx   = (const int*)d_in[4];
  const int*   device_idx   = (const int*)d_in[5];
  const int*   neighbor_idx = (const int*)d_in[6];
  const float* ce0 = (const float*)d_in[7];
  const float* ce1 = (const float*)d_in[8];
  const float* de0 = (const float*)d_in[9];
  const float* de1 = (const float*)d_in[10];
  const float* Wc  = (const float*)d_in[11];
  const float* bc  = (const float*)d_in[12];
  const float* Wd  = (const float*)d_in[13];
  const float* bd  = (const float*)d_in[14];
  const float* aW  = (const float*)d_in[15];
  const float* ab  = (const float*)d_in[16];
  const float* W1  = (const float*)d_in[17];
  const float* b1  = (const float*)d_in[18];
  const float* W2  = (const float*)d_in[19];
  const float* b2  = (const float*)d_in[20];
  const float* W3  = (const float*)d_in[21];
  const float* b3  = (const float*)d_in[22];
  const float* W4  = (const float*)d_in[23];
  const float* b4  = (const float*)d_in[24];

  float* ws  = (float*)d_ws;
  ushortT* h_bf = (ushortT*)ws;
  float* e_d = ws + 3200000;
  float* e_c = ws + 3600000;
  uintT* wpack = (uintT*)(ws + 3632768);

  k_prep<<<24, 256, 0, stream>>>(Wd, Wc, wpack);
  k_feat<<<NDEVG2 + NCOMBG2, 256, 0, stream>>>(
      device_cont, device_cat, de0, de1, bd,
      combin_cont, combin_cat, combin_idx, ce0, ce1, bc, aW, wpack,
      h_bf, e_d, e_c);
  k_attn<<<2048, 256, 0, stream>>>(
      neighbor_idx, device_idx, device_cat, device_cont, de0, de1,
      combin_idx, combin_cat, combin_cont, ce0, ce1,
      h_bf, e_d, e_c, ab, W1, b1, W2, b2, W3, b3, W4, b4, (float*)d_out);
}

// Round 5
// 165.400 us; speedup vs baseline: 1.1067x; 1.0253x over previous
//
#include <hip/hip_runtime.h>
#include <cmath>

#define NDEV   100000
#define NBATCH 8192
#define CONTF  62
#define EMB    16
#define FEAT   94      // 62 + 16 + 16
#define KNBR   64
#define NH     4
#define OUTD   16
#define HOUT   64      // NH*OUTD
#define FUS    204     // 94 + 94 + 16
#define ALPHA  0.2f

#define NDEVG2  782    // ceil(100000/128) row-groups
#define NCOMBG2 64     // 8192/128 row-groups
#define KP      48     // K-pairs incl. zero pad (96 bf16 = 48 uints)

typedef unsigned short ushortT;
typedef unsigned int   uintT;
typedef ushortT ushort8v __attribute__((ext_vector_type(8)));
typedef short   short8  __attribute__((ext_vector_type(8)));
typedef float   float4v __attribute__((ext_vector_type(4)));

// ---------------- workspace layout (float slots) ----------------
// h_bf  : NDEV*64 bf16 = 3,200,000 @ 0   (12.8 MB)
// e_d   : NDEV*4       =   400,000 @ 3,200,000
// e_c   : NBATCH*4     =    32,768 @ 3,600,000
// wpack : 2*64*48 uint =     6,144 @ 3,632,768   (bf16x2-packed W^T, dev|comb)

template <typename T>
__device__ __forceinline__ const T* uniform_ptr(const T* p) {
  uint64_t v = (uint64_t)(uintptr_t)p;
  uint32_t lo = __builtin_amdgcn_readfirstlane((uint32_t)v);
  uint32_t hi = __builtin_amdgcn_readfirstlane((uint32_t)(v >> 32));
  return (const T*)(uintptr_t)(((uint64_t)hi << 32) | lo);
}

__device__ __forceinline__ float bf2f(ushortT u) {
  return __uint_as_float(((unsigned int)u) << 16);
}
__device__ __forceinline__ ushortT f2bf(float f) {
  unsigned int i = __float_as_uint(f);
  unsigned int r = i + 0x7FFFu + ((i >> 16) & 1u);  // round-to-nearest-even
  return (ushortT)(r >> 16);
}
__device__ __forceinline__ uintT pack2(float lo, float hi) {
  return ((uintT)f2bf(hi) << 16) | (uintT)f2bf(lo);
}

union FragU { uint4 u; short8 s; };

// ---------------- K0: pack W^T -> bf16x2 once (layout [n][p], n=h*16+o) -----
__global__ __launch_bounds__(256) void k_prep(
    const float* __restrict__ Wd, const float* __restrict__ Wc,
    uintT* __restrict__ wpack) {
  const int e = blockIdx.x * 256 + threadIdx.x;   // 0..6143
  if (e >= 2 * 64 * KP) return;
  const bool dev = e < 64 * KP;
  const int i = dev ? e : e - 64 * KP;
  const int n = i / KP, p = i - n * KP;
  const int h = n >> 4, o = n & 15;
  const float* __restrict__ Ws = dev ? Wd : Wc;
  uintT v = 0u;
  if (p < 47) {
    const float lo = Ws[(h * FEAT + 2 * p) * OUTD + o];
    const float hi = Ws[(h * FEAT + 2 * p + 1) * OUTD + o];
    v = pack2(lo, hi);
  }
  wpack[e] = v;
}

// ---------------- K1: X[row,94] @ W[94,64] via bf16 MFMA, 128 rows/block ----
// 4 waves; wave wv owns row-tiles {wv*16, 64+wv*16}, all 4 col-tiles.
// W staged once per block (prepacked); B-frags reused across both row-tiles.
__global__ __launch_bounds__(256, 2) void k_feat(
    const float* __restrict__ device_cont, const int* __restrict__ device_cat,
    const float* __restrict__ de0, const float* __restrict__ de1,
    const float* __restrict__ bd,
    const float* __restrict__ combin_cont, const int* __restrict__ combin_cat,
    const int* __restrict__ combin_idx,
    const float* __restrict__ ce0, const float* __restrict__ ce1,
    const float* __restrict__ bc,
    const float* __restrict__ aW, const uintT* __restrict__ wpack,
    ushortT* __restrict__ h_bf, float* __restrict__ e_d, float* __restrict__ e_c) {
  __shared__ uintT x_s[128 * KP];  // 24,576 B  [row][kpair]
  __shared__ uintT w_s[64 * KP];   // 12,288 B  [col n][kpair]
  __shared__ int   ci_s[128];

  const int tid  = threadIdx.x;
  const int lane = tid & 63;
  const int wv = __builtin_amdgcn_readfirstlane((int)(tid >> 6));
  const int blk = blockIdx.x;
  const bool devp = blk < NDEVG2;
  const int b0 = (devp ? blk : blk - NDEVG2) * 128;

  if (!devp && tid < 128) ci_s[tid] = combin_idx[b0 + tid];

  // ---- stage W: linear uint4 copy of the prepacked slab (768 uint4) ----
  {
    const uint4* __restrict__ wp =
        reinterpret_cast<const uint4*>(wpack + (devp ? 0 : 64 * KP));
#pragma unroll
    for (int t = 0; t < 3; ++t)
      reinterpret_cast<uint4*>(w_s)[t * 256 + tid] = wp[t * 256 + tid];
  }
  __syncthreads();  // ci_s visible

  // ---- stage x: cont pairs (128*31 = 3968) ----
  {
    const float* __restrict__ cont = devp ? device_cont : combin_cont;
#pragma unroll 1
    for (int e = tid; e < 128 * 31; e += 256) {
      const int r = e / 31, p = e - r * 31;
      const size_t srow = devp ? (size_t)min(b0 + r, NDEV - 1) : (size_t)ci_s[r];
      const float2 v = *reinterpret_cast<const float2*>(cont + srow * CONTF + 2 * p);
      x_s[r * KP + p] = pack2(v.x, v.y);
    }
  }
  // ---- stage embeddings: all 256 threads, one (row, table) each ----
  {
    const int r = tid >> 1, tb = tid & 1;  // r in 0..127
    const int srow = devp ? min(b0 + r, NDEV - 1) : ci_s[r];
    const int cidx = (devp ? device_cat : combin_cat)[2 * srow + tb];
    const float* __restrict__ ep =
        (tb ? (devp ? de1 : ce1) : (devp ? de0 : ce0)) + (size_t)cidx * EMB;
    uintT* __restrict__ dst = &x_s[r * KP + 31 + tb * 8];
#pragma unroll
    for (int k4 = 0; k4 < 4; ++k4) {
      const float4 v = reinterpret_cast<const float4*>(ep)[k4];
      dst[2 * k4 + 0] = pack2(v.x, v.y);
      dst[2 * k4 + 1] = pack2(v.z, v.w);
    }
  }
  if (tid < 128) x_s[tid * KP + 47] = 0u;         // k = 94,95 zero pad
  __syncthreads();

  // ---- MFMA compute ----
  const int m = lane & 15, q = lane >> 4;
  const float* bias = uniform_ptr(devp ? bd : bc);
  const float* aWl  = uniform_ptr(aW);

  float4v acc[2][NH];
#pragma unroll
  for (int ct = 0; ct < NH; ++ct) {
    const float bv = bias[ct * OUTD + m];
    acc[0][ct] = (float4v){bv, bv, bv, bv};
    acc[1][ct] = (float4v){bv, bv, bv, bv};
  }

  const uintT* xa0 = &x_s[(wv * 16 + m) * KP + q * 4];
  const uintT* xa1 = &x_s[(64 + wv * 16 + m) * KP + q * 4];
#pragma unroll
  for (int c = 0; c < 3; ++c) {                  // K chunks of 32
    FragU af0, af1;
    af0.u = *reinterpret_cast<const uint4*>(xa0 + c * 16);
    af1.u = *reinterpret_cast<const uint4*>(xa1 + c * 16);
#pragma unroll
    for (int ct = 0; ct < NH; ++ct) {
      FragU bf;
      bf.u = *reinterpret_cast<const uint4*>(&w_s[(ct * 16 + m) * KP + c * 16 + q * 4]);
      acc[0][ct] = __builtin_amdgcn_mfma_f32_16x16x32_bf16(af0.s, bf.s, acc[0][ct], 0, 0, 0);
      acc[1][ct] = __builtin_amdgcn_mfma_f32_16x16x32_bf16(af1.s, bf.s, acc[1][ct], 0, 0, 0);
    }
  }

  // ---- epilogue: e logits + h store, per row-tile ----
  const int aoff = devp ? OUTD : 0;
  float* __restrict__ eout = devp ? e_d : e_c;
#pragma unroll
  for (int rt = 0; rt < 2; ++rt) {
    const int rowq = b0 + rt * 64 + wv * 16 + q * 4;  // first of 4 rows
#pragma unroll
    for (int ct = 0; ct < NH; ++ct) {
      const float av = aWl[ct * 2 * OUTD + aoff + m];
      float e0 = acc[rt][ct][0] * av, e1 = acc[rt][ct][1] * av,
            e2 = acc[rt][ct][2] * av, e3 = acc[rt][ct][3] * av;
#pragma unroll
      for (int msk = 1; msk < 16; msk <<= 1) {
        e0 += __shfl_xor(e0, msk);
        e1 += __shfl_xor(e1, msk);
        e2 += __shfl_xor(e2, msk);
        e3 += __shfl_xor(e3, msk);
      }
      if (m == ct) {
        const float ev[4] = {e0, e1, e2, e3};
#pragma unroll
        for (int r = 0; r < 4; ++r)
          if (!devp || rowq + r < NDEV) eout[(size_t)(rowq + r) * NH + ct] = ev[r];
      }
    }
    if (devp) {
#pragma unroll
      for (int ct = 0; ct < NH; ++ct) {
#pragma unroll
        for (int r = 0; r < 4; ++r) {
          if (rowq + r < NDEV)
            h_bf[(size_t)(rowq + r) * HOUT + ct * OUTD + m] = f2bf(acc[rt][ct][r]);
        }
      }
    }
  }
}

// ---------------- K2: attention + fusion + MLP, fused (one wave = one row) --
// v5: v4 structure (1 row/wave, 9.75 KB LDS, 4 blocks/CU, early h prefetch,
// no-max softmax) with all uniform/aligned LDS reads vectorized to b128 and
// the long fma chains split into independent accumulators:
//   phase D: 204 ds_read_b32 -> 51 ds_read_b128, 4 accs
//   layer 2: 32 -> 8 b128, 4 accs;  phase C: 16 -> 4 b128;  phase B pb: 8 -> 2
// No numeric-path change beyond fp32 reassociation.
__global__ __launch_bounds__(256, 4) void k_attn(
    const int* __restrict__ neighbor_idx, const int* __restrict__ device_idx,
    const int* __restrict__ device_cat, const float* __restrict__ device_cont,
    const float* __restrict__ de0, const float* __restrict__ de1,
    const int* __restrict__ combin_idx, const int* __restrict__ combin_cat,
    const float* __restrict__ combin_cont,
    const float* __restrict__ ce0, const float* __restrict__ ce1,
    const ushortT* __restrict__ h_bf, const float* __restrict__ e_d,
    const float* __restrict__ e_c, const float* __restrict__ ab,
    const float* __restrict__ W1, const float* __restrict__ b1,
    const float* __restrict__ W2, const float* __restrict__ b2,
    const float* __restrict__ W3, const float* __restrict__ b3,
    const float* __restrict__ W4, const float* __restrict__ b4,
    float* __restrict__ out) {
  __shared__ __align__(16) float pb[4][NH][68];
  __shared__ __align__(16) float hb[4][HOUT];
  __shared__ __align__(16) float fusb[4][208];   // fusion row (204 + pad)
  __shared__ __align__(16) float x1b[4][64];

  const int lane = threadIdx.x & 63;
  const int wid  = __builtin_amdgcn_readfirstlane((int)(threadIdx.x >> 6));
  const int b    = blockIdx.x * 4 + wid;

  // ---- phase A0: neighbor index + e gathers issued first ----
  const int nk = neighbor_idx[(size_t)b * KNBR + lane];
  const float4 ed4 = *reinterpret_cast<const float4*>(e_d + (size_t)nk * NH);
  const float4 ec4 = *reinterpret_cast<const float4*>(e_c + (size_t)b * NH);
  const float4 ab4 = *reinterpret_cast<const float4*>(ab);

  // ---- phase A1: EARLY h_bf prefetch for this lane's phase-B slice ----
  const int q = lane >> 3, c8 = lane & 7;
  ushort8v hpre[8];
#pragma unroll
  for (int t = 0; t < 8; ++t) {
    const int nt = __shfl(nk, q * 8 + t);
    hpre[t] = *reinterpret_cast<const ushort8v*>(h_bf + (size_t)nt * HOUT + c8 * 8);
  }

  // ---- phase A2: gather fusion features [comb 94 | dev 94] into LDS ----
  const int ci = combin_idx[b];
  const int cc0 = combin_cat[2 * ci], cc1 = combin_cat[2 * ci + 1];
  const int didx = device_idx[b];
  const int dc0 = device_cat[2 * didx], dc1 = device_cat[2 * didx + 1];
#pragma unroll
  for (int t = 0; t < 3; ++t) {
    const int i = lane + t * 64;
    if (i < 188) {
      float v;
      if (i < 62)       v = combin_cont[(size_t)ci * CONTF + i];
      else if (i < 78)  v = ce0[(size_t)cc0 * EMB + (i - 62)];
      else if (i < 94)  v = ce1[(size_t)cc1 * EMB + (i - 78)];
      else if (i < 156) v = device_cont[(size_t)didx * CONTF + (i - 94)];
      else if (i < 172) v = de0[(size_t)dc0 * EMB + (i - 156)];
      else              v = de1[(size_t)dc1 * EMB + (i - 172)];
      fusb[wid][i] = v;
    }
  }

  // ---- phase A3: softmax over neighbors (lane = k), no max-subtract ----
  float v0 = ec4.x + ed4.x + ab4.x;
  float v1 = ec4.y + ed4.y + ab4.y;
  float v2 = ec4.z + ed4.z + ab4.z;
  float v3 = ec4.w + ed4.w + ab4.w;
  v0 = v0 > 0.f ? v0 : ALPHA * v0;
  v1 = v1 > 0.f ? v1 : ALPHA * v1;
  v2 = v2 > 0.f ? v2 : ALPHA * v2;
  v3 = v3 > 0.f ? v3 : ALPHA * v3;

  float p0 = expf(v0), p1 = expf(v1), p2 = expf(v2), p3 = expf(v3);
  float s0 = p0, s1 = p1, s2 = p2, s3 = p3;
#pragma unroll
  for (int msk = 1; msk < 64; msk <<= 1) {
    s0 += __shfl_xor(s0, msk);
    s1 += __shfl_xor(s1, msk);
    s2 += __shfl_xor(s2, msk);
    s3 += __shfl_xor(s3, msk);
  }
  p0 /= s0; p1 /= s1; p2 /= s2; p3 /= s3;

  pb[wid][0][lane] = p0;
  pb[wid][1][lane] = p1;
  pb[wid][2][lane] = p2;
  pb[wid][3][lane] = p3;
  __builtin_amdgcn_wave_barrier();

  // ---- phase B: weighted sum from prefetched h regs, lane = (q, c8) ----
  {
    const int hq = c8 >> 1;
    const float4 pA4 = *reinterpret_cast<const float4*>(&pb[wid][hq][q * 8]);
    const float4 pB4 = *reinterpret_cast<const float4*>(&pb[wid][hq][q * 8 + 4]);
    const float pv[8] = {pA4.x, pA4.y, pA4.z, pA4.w,
                         pB4.x, pB4.y, pB4.z, pB4.w};
    float a[8];
#pragma unroll
    for (int i = 0; i < 8; ++i) a[i] = 0.f;
#pragma unroll
    for (int t = 0; t < 8; ++t) {
      const float p = pv[t];
#pragma unroll
      for (int i = 0; i < 8; ++i) a[i] = fmaf(p, bf2f(hpre[t][i]), a[i]);
    }
#pragma unroll
    for (int msk = 8; msk < 64; msk <<= 1) {
#pragma unroll
      for (int i = 0; i < 8; ++i) a[i] += __shfl_xor(a[i], msk);
    }
    if (q == 0) {
#pragma unroll
      for (int i = 0; i < 8; ++i) a[i] = a[i] > 0.f ? a[i] : expm1f(a[i]);  // elu
      float4* hp = reinterpret_cast<float4*>(&hb[wid][c8 * 8]);
      hp[0] = make_float4(a[0], a[1], a[2], a[3]);
      hp[1] = make_float4(a[4], a[5], a[6], a[7]);
    }
  }
  __builtin_amdgcn_wave_barrier();

  // ---- phase C: attn_feats = head_out(64) @ W1(64x16) + b1 -> fusb[188..] --
  {
    const int j = lane & 15, gg = lane >> 4;
    const float4* hv4 = reinterpret_cast<const float4*>(&hb[wid][gg * 16]);
    float pc0 = 0.f, pc1 = 0.f;
#pragma unroll
    for (int t4 = 0; t4 < 4; ++t4) {
      const float4 hv = hv4[t4];
      const int tb = gg * 16 + t4 * 4;
      pc0 = fmaf(hv.x, W1[(tb + 0) * OUTD + j], pc0);
      pc1 = fmaf(hv.y, W1[(tb + 1) * OUTD + j], pc1);
      pc0 = fmaf(hv.z, W1[(tb + 2) * OUTD + j], pc0);
      pc1 = fmaf(hv.w, W1[(tb + 3) * OUTD + j], pc1);
    }
    float part = pc0 + pc1;
    part += __shfl_xor(part, 16);
    part += __shfl_xor(part, 32);
    if (lane < 16) fusb[wid][188 + lane] = part + b1[lane];
  }
  __builtin_amdgcn_wave_barrier();

  // ---- phase D: MLP layer 1 (204 -> 64), lane = output col; b128 reads ----
  {
    float a0 = b2[lane], a1 = 0.f, a2 = 0.f, a3 = 0.f;
    const float4* fu4 = reinterpret_cast<const float4*>(fusb[wid]);
#pragma unroll 3
    for (int f4 = 0; f4 < 51; ++f4) {
      const float4 u = fu4[f4];
      const int fb = f4 * 4;
      a0 = fmaf(u.x, W2[(fb + 0) * 64 + lane], a0);
      a1 = fmaf(u.y, W2[(fb + 1) * 64 + lane], a1);
      a2 = fmaf(u.z, W2[(fb + 2) * 64 + lane], a2);
      a3 = fmaf(u.w, W2[(fb + 3) * 64 + lane], a3);
    }
    x1b[wid][lane] = fmaxf((a0 + a1) + (a2 + a3), 0.f);
  }
  __builtin_amdgcn_wave_barrier();

  // ---- layers 2+3 + sigmoid ----
  const int m = lane & 31, rh = lane >> 5;
  {
    float x2a = rh ? 0.f : b3[m], x2b = 0.f, x2c = 0.f, x2d = 0.f;
    const float4* xv4 = reinterpret_cast<const float4*>(&x1b[wid][rh * 32]);
#pragma unroll
    for (int j4 = 0; j4 < 8; ++j4) {
      const float4 xv = xv4[j4];
      const int jb = rh * 32 + j4 * 4;
      x2a = fmaf(xv.x, W3[(jb + 0) * 32 + m], x2a);
      x2b = fmaf(xv.y, W3[(jb + 1) * 32 + m], x2b);
      x2c = fmaf(xv.z, W3[(jb + 2) * 32 + m], x2c);
      x2d = fmaf(xv.w, W3[(jb + 3) * 32 + m], x2d);
    }
    float x2 = (x2a + x2b) + (x2c + x2d);
    x2 += __shfl_xor(x2, 32);                    // combine j-halves
    float pL3 = fmaxf(x2, 0.f) * W4[m];
#pragma unroll
    for (int msk = 1; msk < 32; msk <<= 1) pL3 += __shfl_xor(pL3, msk);
    if (lane == 0) {
      const float z = pL3 + b4[0];
      out[b] = 1.f / (1.f + expf(-z));
    }
  }
}

extern "C" void kernel_launch(void* const* d_in, const int* in_sizes, int n_in,
                              void* d_out, int out_size, void* d_ws, size_t ws_size,
                              hipStream_t stream) {
  const float* combin_cont  = (const float*)d_in[0];
  const int*   combin_cat   = (const int*)d_in[1];
  const float* device_cont  = (const float*)d_in[2];
  const int*   device_cat   = (const int*)d_in[3];
  const int*   combin_idx   = (const int*)d_in[4];
  const int*   device_idx   = (const int*)d_in[5];
  const int*   neighbor_idx = (const int*)d_in[6];
  const float* ce0 = (const float*)d_in[7];
  const float* ce1 = (const float*)d_in[8];
  const float* de0 = (const float*)d_in[9];
  const float* de1 = (const float*)d_in[10];
  const float* Wc  = (const float*)d_in[11];
  const float* bc  = (const float*)d_in[12];
  const float* Wd  = (const float*)d_in[13];
  const float* bd  = (const float*)d_in[14];
  const float* aW  = (const float*)d_in[15];
  const float* ab  = (const float*)d_in[16];
  const float* W1  = (const float*)d_in[17];
  const float* b1  = (const float*)d_in[18];
  const float* W2  = (const float*)d_in[19];
  const float* b2  = (const float*)d_in[20];
  const float* W3  = (const float*)d_in[21];
  const float* b3  = (const float*)d_in[22];
  const float* W4  = (const float*)d_in[23];
  const float* b4  = (const float*)d_in[24];

  float* ws  = (float*)d_ws;
  ushortT* h_bf = (ushortT*)ws;
  float* e_d = ws + 3200000;
  float* e_c = ws + 3600000;
  uintT* wpack = (uintT*)(ws + 3632768);

  k_prep<<<24, 256, 0, stream>>>(Wd, Wc, wpack);
  k_feat<<<NDEVG2 + NCOMBG2, 256, 0, stream>>>(
      device_cont, device_cat, de0, de1, bd,
      combin_cont, combin_cat, combin_idx, ce0, ce1, bc, aW, wpack,
      h_bf, e_d, e_c);
  k_attn<<<2048, 256, 0, stream>>>(
      neighbor_idx, device_idx, device_cat, device_cont, de0, de1,
      combin_idx, combin_cat, combin_cont, ce0, ce1,
      h_bf, e_d, e_c, ab, W1, b1, W2, b2, W3, b3, W4, b4, (float*)d_out);
}

// Round 6
// 161.212 us; speedup vs baseline: 1.1354x; 1.0260x over previous
//
#include <hip/hip_runtime.h>
#include <cmath>

#define NDEV   100000
#define NBATCH 8192
#define CONTF  62
#define EMB    16
#define FEAT   94      // 62 + 16 + 16
#define KNBR   64
#define NH     4
#define OUTD   16
#define HOUT   64      // NH*OUTD
#define FUS    204     // 94 + 94 + 16
#define ALPHA  0.2f

#define NDEVG2  782    // ceil(100000/128) row-groups
#define NCOMBG2 64     // 8192/128 row-groups
#define KP      48     // K-pairs incl. zero pad (96 bf16 = 48 uints)
#define WROWS   68     // 64 W cols + 4 e-logit (a-weighted) cols

typedef unsigned short ushortT;
typedef unsigned int   uintT;
typedef ushortT ushort8v __attribute__((ext_vector_type(8)));
typedef short   short8  __attribute__((ext_vector_type(8)));
typedef float   float4v __attribute__((ext_vector_type(4)));

// ---------------- workspace layout (float slots) ----------------
// h_bf  : NDEV*64 bf16 = 3,200,000 @ 0   (12.8 MB)
// e_d   : NDEV*4       =   400,000 @ 3,200,000
// e_c   : NBATCH*4     =    32,768 @ 3,600,000
// wpack : 2*68*48 uint =     6,528 @ 3,632,768   (bf16x2-packed W^T+waug)

template <typename T>
__device__ __forceinline__ const T* uniform_ptr(const T* p) {
  uint64_t v = (uint64_t)(uintptr_t)p;
  uint32_t lo = __builtin_amdgcn_readfirstlane((uint32_t)v);
  uint32_t hi = __builtin_amdgcn_readfirstlane((uint32_t)(v >> 32));
  return (const T*)(uintptr_t)(((uint64_t)hi << 32) | lo);
}

__device__ __forceinline__ float bf2f(ushortT u) {
  return __uint_as_float(((unsigned int)u) << 16);
}
__device__ __forceinline__ ushortT f2bf(float f) {
  unsigned int i = __float_as_uint(f);
  unsigned int r = i + 0x7FFFu + ((i >> 16) & 1u);  // round-to-nearest-even
  return (ushortT)(r >> 16);
}
__device__ __forceinline__ uintT pack2(float lo, float hi) {
  return ((uintT)f2bf(hi) << 16) | (uintT)f2bf(lo);
}

union FragU { uint4 u; short8 s; };

// ---------------- K0: pack W^T -> bf16x2 once (layout [n][p], n=h*16+o) -----
// Rows 64..67: waug[hd][f] = sum_o W[hd][f][o] * a_seg[hd][o]  (e-logit cols;
// a_seg = a2 for dev path, a1 for comb path). e = X @ waug + (b . a) is the
// leaky-relu input logit — computed by the SAME MFMA as h in k_feat.
__global__ __launch_bounds__(256) void k_prep(
    const float* __restrict__ Wd, const float* __restrict__ Wc,
    const float* __restrict__ aW,
    uintT* __restrict__ wpack) {
  const int e = blockIdx.x * 256 + threadIdx.x;   // 0..6527
  if (e >= 2 * WROWS * KP) return;
  const bool dev = e < WROWS * KP;
  const int i = dev ? e : e - WROWS * KP;
  const int n = i / KP, p = i - n * KP;
  const float* __restrict__ Ws = dev ? Wd : Wc;
  uintT v = 0u;
  if (p < 47) {
    if (n < 64) {
      const int h = n >> 4, o = n & 15;
      const float lo = Ws[(h * FEAT + 2 * p) * OUTD + o];
      const float hi = Ws[(h * FEAT + 2 * p + 1) * OUTD + o];
      v = pack2(lo, hi);
    } else {
      const int hd = n - 64;                       // 0..3
      const float* __restrict__ av = aW + hd * 2 * OUTD + (dev ? OUTD : 0);
      float lo = 0.f, hi = 0.f;
#pragma unroll
      for (int o = 0; o < OUTD; ++o) {
        lo = fmaf(Ws[(hd * FEAT + 2 * p) * OUTD + o], av[o], lo);
        hi = fmaf(Ws[(hd * FEAT + 2 * p + 1) * OUTD + o], av[o], hi);
      }
      v = pack2(lo, hi);
    }
  }
  wpack[e] = v;
}

// ---------------- K1: X[row,94] @ W[94,68] via bf16 MFMA, 128 rows/block ----
// 4 waves; wave wv owns row-tiles {wv*16, 64+wv*16}; 4 h col-tiles + 1 e-tile
// (cols 64..67 live, 68..79 zero). Epilogue is pure stores — the 128-shfl
// e-reduce of earlier versions is replaced by 6 extra MFMAs.
__global__ __launch_bounds__(256, 2) void k_feat(
    const float* __restrict__ device_cont, const int* __restrict__ device_cat,
    const float* __restrict__ de0, const float* __restrict__ de1,
    const float* __restrict__ bd,
    const float* __restrict__ combin_cont, const int* __restrict__ combin_cat,
    const int* __restrict__ combin_idx,
    const float* __restrict__ ce0, const float* __restrict__ ce1,
    const float* __restrict__ bc,
    const float* __restrict__ aW, const uintT* __restrict__ wpack,
    ushortT* __restrict__ h_bf, float* __restrict__ e_d, float* __restrict__ e_c) {
  __shared__ uintT x_s[128 * KP];  // 24,576 B  [row][kpair]
  __shared__ uintT w_s[80 * KP];   // 15,360 B  [col n][kpair], rows 68..79 = 0
  __shared__ int   ci_s[128];

  const int tid  = threadIdx.x;
  const int lane = tid & 63;
  const int wv = __builtin_amdgcn_readfirstlane((int)(tid >> 6));
  const int blk = blockIdx.x;
  const bool devp = blk < NDEVG2;
  const int b0 = (devp ? blk : blk - NDEVG2) * 128;

  if (!devp && tid < 128) ci_s[tid] = combin_idx[b0 + tid];

  // ---- stage W: linear uint4 copy of prepacked slab (816 uint4) + zero tail
  {
    const uint4* __restrict__ wp =
        reinterpret_cast<const uint4*>(wpack + (devp ? 0 : WROWS * KP));
    uint4* __restrict__ ws4 = reinterpret_cast<uint4*>(w_s);
#pragma unroll
    for (int t = 0; t < 4; ++t) {
      const int idx = t * 256 + tid;
      if (idx < 960)                     // 80 rows * 12 uint4
        ws4[idx] = (idx < 816) ? wp[idx] : make_uint4(0u, 0u, 0u, 0u);
    }
  }
  __syncthreads();  // ci_s visible

  // ---- stage x: cont pairs (128*31 = 3968) ----
  {
    const float* __restrict__ cont = devp ? device_cont : combin_cont;
#pragma unroll 1
    for (int e = tid; e < 128 * 31; e += 256) {
      const int r = e / 31, p = e - r * 31;
      const size_t srow = devp ? (size_t)min(b0 + r, NDEV - 1) : (size_t)ci_s[r];
      const float2 v = *reinterpret_cast<const float2*>(cont + srow * CONTF + 2 * p);
      x_s[r * KP + p] = pack2(v.x, v.y);
    }
  }
  // ---- stage embeddings: all 256 threads, one (row, table) each ----
  {
    const int r = tid >> 1, tb = tid & 1;  // r in 0..127
    const int srow = devp ? min(b0 + r, NDEV - 1) : ci_s[r];
    const int cidx = (devp ? device_cat : combin_cat)[2 * srow + tb];
    const float* __restrict__ ep =
        (tb ? (devp ? de1 : ce1) : (devp ? de0 : ce0)) + (size_t)cidx * EMB;
    uintT* __restrict__ dst = &x_s[r * KP + 31 + tb * 8];
#pragma unroll
    for (int k4 = 0; k4 < 4; ++k4) {
      const float4 v = reinterpret_cast<const float4*>(ep)[k4];
      dst[2 * k4 + 0] = pack2(v.x, v.y);
      dst[2 * k4 + 1] = pack2(v.z, v.w);
    }
  }
  if (tid < 128) x_s[tid * KP + 47] = 0u;         // k = 94,95 zero pad
  __syncthreads();

  // ---- MFMA compute ----
  const int m = lane & 15, q = lane >> 4;
  const int aoff = devp ? OUTD : 0;
  const float* bias = uniform_ptr(devp ? bd : bc);
  const float* aWl  = uniform_ptr(aW);

  float4v acc[2][NH];
#pragma unroll
  for (int ct = 0; ct < NH; ++ct) {
    const float bv = bias[ct * OUTD + m];
    acc[0][ct] = (float4v){bv, bv, bv, bv};
    acc[1][ct] = (float4v){bv, bv, bv, bv};
  }
  // e-accumulator init: bias-dot const for col hd=m (m<4), else 0
  float bec = 0.f;
  if (m < NH) {
    const float* __restrict__ av = aWl + m * 2 * OUTD + aoff;
#pragma unroll
    for (int o = 0; o < OUTD; ++o) bec = fmaf(bias[m * OUTD + o], av[o], bec);
  }
  float4v acc_e[2];
  acc_e[0] = (float4v){bec, bec, bec, bec};
  acc_e[1] = (float4v){bec, bec, bec, bec};

  const uintT* xa0 = &x_s[(wv * 16 + m) * KP + q * 4];
  const uintT* xa1 = &x_s[(64 + wv * 16 + m) * KP + q * 4];
#pragma unroll
  for (int c = 0; c < 3; ++c) {                  // K chunks of 32
    FragU af0, af1;
    af0.u = *reinterpret_cast<const uint4*>(xa0 + c * 16);
    af1.u = *reinterpret_cast<const uint4*>(xa1 + c * 16);
#pragma unroll
    for (int ct = 0; ct < NH; ++ct) {
      FragU bf;
      bf.u = *reinterpret_cast<const uint4*>(&w_s[(ct * 16 + m) * KP + c * 16 + q * 4]);
      acc[0][ct] = __builtin_amdgcn_mfma_f32_16x16x32_bf16(af0.s, bf.s, acc[0][ct], 0, 0, 0);
      acc[1][ct] = __builtin_amdgcn_mfma_f32_16x16x32_bf16(af1.s, bf.s, acc[1][ct], 0, 0, 0);
    }
    FragU bfe;
    bfe.u = *reinterpret_cast<const uint4*>(&w_s[(64 + m) * KP + c * 16 + q * 4]);
    acc_e[0] = __builtin_amdgcn_mfma_f32_16x16x32_bf16(af0.s, bfe.s, acc_e[0], 0, 0, 0);
    acc_e[1] = __builtin_amdgcn_mfma_f32_16x16x32_bf16(af1.s, bfe.s, acc_e[1], 0, 0, 0);
  }

  // ---- epilogue: pure stores (e from acc_e, h from acc) ----
  float* __restrict__ eout = devp ? e_d : e_c;
#pragma unroll
  for (int rt = 0; rt < 2; ++rt) {
    const int rowq = b0 + rt * 64 + wv * 16 + q * 4;  // first of 4 rows
    if (m < NH) {
#pragma unroll
      for (int r = 0; r < 4; ++r)
        if (!devp || rowq + r < NDEV) eout[(size_t)(rowq + r) * NH + m] = acc_e[rt][r];
    }
    if (devp) {
#pragma unroll
      for (int ct = 0; ct < NH; ++ct) {
#pragma unroll
        for (int r = 0; r < 4; ++r) {
          if (rowq + r < NDEV)
            h_bf[(size_t)(rowq + r) * HOUT + ct * OUTD + m] = f2bf(acc[rt][ct][r]);
        }
      }
    }
  }
}

// ---------------- K2: attention + fusion + MLP, fused (one wave = one row) --
// v5's k_attn unchanged: 1 row/wave, 9.75 KB LDS, 4 blocks/CU; early
// __shfl-indexed h_bf prefetch; no-max softmax; b128 LDS reads + split accs.
__global__ __launch_bounds__(256, 4) void k_attn(
    const int* __restrict__ neighbor_idx, const int* __restrict__ device_idx,
    const int* __restrict__ device_cat, const float* __restrict__ device_cont,
    const float* __restrict__ de0, const float* __restrict__ de1,
    const int* __restrict__ combin_idx, const int* __restrict__ combin_cat,
    const float* __restrict__ combin_cont,
    const float* __restrict__ ce0, const float* __restrict__ ce1,
    const ushortT* __restrict__ h_bf, const float* __restrict__ e_d,
    const float* __restrict__ e_c, const float* __restrict__ ab,
    const float* __restrict__ W1, const float* __restrict__ b1,
    const float* __restrict__ W2, const float* __restrict__ b2,
    const float* __restrict__ W3, const float* __restrict__ b3,
    const float* __restrict__ W4, const float* __restrict__ b4,
    float* __restrict__ out) {
  __shared__ __align__(16) float pb[4][NH][68];
  __shared__ __align__(16) float hb[4][HOUT];
  __shared__ __align__(16) float fusb[4][208];   // fusion row (204 + pad)
  __shared__ __align__(16) float x1b[4][64];

  const int lane = threadIdx.x & 63;
  const int wid  = __builtin_amdgcn_readfirstlane((int)(threadIdx.x >> 6));
  const int b    = blockIdx.x * 4 + wid;

  // ---- phase A0: neighbor index + e gathers issued first ----
  const int nk = neighbor_idx[(size_t)b * KNBR + lane];
  const float4 ed4 = *reinterpret_cast<const float4*>(e_d + (size_t)nk * NH);
  const float4 ec4 = *reinterpret_cast<const float4*>(e_c + (size_t)b * NH);
  const float4 ab4 = *reinterpret_cast<const float4*>(ab);

  // ---- phase A1: EARLY h_bf prefetch for this lane's phase-B slice ----
  const int q = lane >> 3, c8 = lane & 7;
  ushort8v hpre[8];
#pragma unroll
  for (int t = 0; t < 8; ++t) {
    const int nt = __shfl(nk, q * 8 + t);
    hpre[t] = *reinterpret_cast<const ushort8v*>(h_bf + (size_t)nt * HOUT + c8 * 8);
  }

  // ---- phase A2: gather fusion features [comb 94 | dev 94] into LDS ----
  const int ci = combin_idx[b];
  const int cc0 = combin_cat[2 * ci], cc1 = combin_cat[2 * ci + 1];
  const int didx = device_idx[b];
  const int dc0 = device_cat[2 * didx], dc1 = device_cat[2 * didx + 1];
#pragma unroll
  for (int t = 0; t < 3; ++t) {
    const int i = lane + t * 64;
    if (i < 188) {
      float v;
      if (i < 62)       v = combin_cont[(size_t)ci * CONTF + i];
      else if (i < 78)  v = ce0[(size_t)cc0 * EMB + (i - 62)];
      else if (i < 94)  v = ce1[(size_t)cc1 * EMB + (i - 78)];
      else if (i < 156) v = device_cont[(size_t)didx * CONTF + (i - 94)];
      else if (i < 172) v = de0[(size_t)dc0 * EMB + (i - 156)];
      else              v = de1[(size_t)dc1 * EMB + (i - 172)];
      fusb[wid][i] = v;
    }
  }

  // ---- phase A3: softmax over neighbors (lane = k), no max-subtract ----
  float v0 = ec4.x + ed4.x + ab4.x;
  float v1 = ec4.y + ed4.y + ab4.y;
  float v2 = ec4.z + ed4.z + ab4.z;
  float v3 = ec4.w + ed4.w + ab4.w;
  v0 = v0 > 0.f ? v0 : ALPHA * v0;
  v1 = v1 > 0.f ? v1 : ALPHA * v1;
  v2 = v2 > 0.f ? v2 : ALPHA * v2;
  v3 = v3 > 0.f ? v3 : ALPHA * v3;

  float p0 = expf(v0), p1 = expf(v1), p2 = expf(v2), p3 = expf(v3);
  float s0 = p0, s1 = p1, s2 = p2, s3 = p3;
#pragma unroll
  for (int msk = 1; msk < 64; msk <<= 1) {
    s0 += __shfl_xor(s0, msk);
    s1 += __shfl_xor(s1, msk);
    s2 += __shfl_xor(s2, msk);
    s3 += __shfl_xor(s3, msk);
  }
  p0 /= s0; p1 /= s1; p2 /= s2; p3 /= s3;

  pb[wid][0][lane] = p0;
  pb[wid][1][lane] = p1;
  pb[wid][2][lane] = p2;
  pb[wid][3][lane] = p3;
  __builtin_amdgcn_wave_barrier();

  // ---- phase B: weighted sum from prefetched h regs, lane = (q, c8) ----
  {
    const int hq = c8 >> 1;
    const float4 pA4 = *reinterpret_cast<const float4*>(&pb[wid][hq][q * 8]);
    const float4 pB4 = *reinterpret_cast<const float4*>(&pb[wid][hq][q * 8 + 4]);
    const float pv[8] = {pA4.x, pA4.y, pA4.z, pA4.w,
                         pB4.x, pB4.y, pB4.z, pB4.w};
    float a[8];
#pragma unroll
    for (int i = 0; i < 8; ++i) a[i] = 0.f;
#pragma unroll
    for (int t = 0; t < 8; ++t) {
      const float p = pv[t];
#pragma unroll
      for (int i = 0; i < 8; ++i) a[i] = fmaf(p, bf2f(hpre[t][i]), a[i]);
    }
#pragma unroll
    for (int msk = 8; msk < 64; msk <<= 1) {
#pragma unroll
      for (int i = 0; i < 8; ++i) a[i] += __shfl_xor(a[i], msk);
    }
    if (q == 0) {
#pragma unroll
      for (int i = 0; i < 8; ++i) a[i] = a[i] > 0.f ? a[i] : expm1f(a[i]);  // elu
      float4* hp = reinterpret_cast<float4*>(&hb[wid][c8 * 8]);
      hp[0] = make_float4(a[0], a[1], a[2], a[3]);
      hp[1] = make_float4(a[4], a[5], a[6], a[7]);
    }
  }
  __builtin_amdgcn_wave_barrier();

  // ---- phase C: attn_feats = head_out(64) @ W1(64x16) + b1 -> fusb[188..] --
  {
    const int j = lane & 15, gg = lane >> 4;
    const float4* hv4 = reinterpret_cast<const float4*>(&hb[wid][gg * 16]);
    float pc0 = 0.f, pc1 = 0.f;
#pragma unroll
    for (int t4 = 0; t4 < 4; ++t4) {
      const float4 hv = hv4[t4];
      const int tb = gg * 16 + t4 * 4;
      pc0 = fmaf(hv.x, W1[(tb + 0) * OUTD + j], pc0);
      pc1 = fmaf(hv.y, W1[(tb + 1) * OUTD + j], pc1);
      pc0 = fmaf(hv.z, W1[(tb + 2) * OUTD + j], pc0);
      pc1 = fmaf(hv.w, W1[(tb + 3) * OUTD + j], pc1);
    }
    float part = pc0 + pc1;
    part += __shfl_xor(part, 16);
    part += __shfl_xor(part, 32);
    if (lane < 16) fusb[wid][188 + lane] = part + b1[lane];
  }
  __builtin_amdgcn_wave_barrier();

  // ---- phase D: MLP layer 1 (204 -> 64), lane = output col; b128 reads ----
  {
    float a0 = b2[lane], a1 = 0.f, a2 = 0.f, a3 = 0.f;
    const float4* fu4 = reinterpret_cast<const float4*>(fusb[wid]);
#pragma unroll 3
    for (int f4 = 0; f4 < 51; ++f4) {
      const float4 u = fu4[f4];
      const int fb = f4 * 4;
      a0 = fmaf(u.x, W2[(fb + 0) * 64 + lane], a0);
      a1 = fmaf(u.y, W2[(fb + 1) * 64 + lane], a1);
      a2 = fmaf(u.z, W2[(fb + 2) * 64 + lane], a2);
      a3 = fmaf(u.w, W2[(fb + 3) * 64 + lane], a3);
    }
    x1b[wid][lane] = fmaxf((a0 + a1) + (a2 + a3), 0.f);
  }
  __builtin_amdgcn_wave_barrier();

  // ---- layers 2+3 + sigmoid ----
  const int m = lane & 31, rh = lane >> 5;
  {
    float x2a = rh ? 0.f : b3[m], x2b = 0.f, x2c = 0.f, x2d = 0.f;
    const float4* xv4 = reinterpret_cast<const float4*>(&x1b[wid][rh * 32]);
#pragma unroll
    for (int j4 = 0; j4 < 8; ++j4) {
      const float4 xv = xv4[j4];
      const int jb = rh * 32 + j4 * 4;
      x2a = fmaf(xv.x, W3[(jb + 0) * 32 + m], x2a);
      x2b = fmaf(xv.y, W3[(jb + 1) * 32 + m], x2b);
      x2c = fmaf(xv.z, W3[(jb + 2) * 32 + m], x2c);
      x2d = fmaf(xv.w, W3[(jb + 3) * 32 + m], x2d);
    }
    float x2 = (x2a + x2b) + (x2c + x2d);
    x2 += __shfl_xor(x2, 32);                    // combine j-halves
    float pL3 = fmaxf(x2, 0.f) * W4[m];
#pragma unroll
    for (int msk = 1; msk < 32; msk <<= 1) pL3 += __shfl_xor(pL3, msk);
    if (lane == 0) {
      const float z = pL3 + b4[0];
      out[b] = 1.f / (1.f + expf(-z));
    }
  }
}

extern "C" void kernel_launch(void* const* d_in, const int* in_sizes, int n_in,
                              void* d_out, int out_size, void* d_ws, size_t ws_size,
                              hipStream_t stream) {
  const float* combin_cont  = (const float*)d_in[0];
  const int*   combin_cat   = (const int*)d_in[1];
  const float* device_cont  = (const float*)d_in[2];
  const int*   device_cat   = (const int*)d_in[3];
  const int*   combin_idx   = (const int*)d_in[4];
  const int*   device_idx   = (const int*)d_in[5];
  const int*   neighbor_idx = (const int*)d_in[6];
  const float* ce0 = (const float*)d_in[7];
  const float* ce1 = (const float*)d_in[8];
  const float* de0 = (const float*)d_in[9];
  const float* de1 = (const float*)d_in[10];
  const float* Wc  = (const float*)d_in[11];
  const float* bc  = (const float*)d_in[12];
  const float* Wd  = (const float*)d_in[13];
  const float* bd  = (const float*)d_in[14];
  const float* aW  = (const float*)d_in[15];
  const float* ab  = (const float*)d_in[16];
  const float* W1  = (const float*)d_in[17];
  const float* b1  = (const float*)d_in[18];
  const float* W2  = (const float*)d_in[19];
  const float* b2  = (const float*)d_in[20];
  const float* W3  = (const float*)d_in[21];
  const float* b3  = (const float*)d_in[22];
  const float* W4  = (const float*)d_in[23];
  const float* b4  = (const float*)d_in[24];

  float* ws  = (float*)d_ws;
  ushortT* h_bf = (ushortT*)ws;
  float* e_d = ws + 3200000;
  float* e_c = ws + 3600000;
  uintT* wpack = (uintT*)(ws + 3632768);

  k_prep<<<26, 256, 0, stream>>>(Wd, Wc, aW, wpack);
  k_feat<<<NDEVG2 + NCOMBG2, 256, 0, stream>>>(
      device_cont, device_cat, de0, de1, bd,
      combin_cont, combin_cat, combin_idx, ce0, ce1, bc, aW, wpack,
      h_bf, e_d, e_c);
  k_attn<<<2048, 256, 0, stream>>>(
      neighbor_idx, device_idx, device_cat, device_cont, de0, de1,
      combin_idx, combin_cat, combin_cont, ce0, ce1,
      h_bf, e_d, e_c, ab, W1, b1, W2, b2, W3, b3, W4, b4, (float*)d_out);
}